// Round 18
// baseline (131.286 us; speedup 1.0000x reference)
//
#include <hip/hip_runtime.h>

// ---------- types ----------
typedef __bf16 bf16x8 __attribute__((ext_vector_type(8)));
typedef float f32x4 __attribute__((ext_vector_type(4)));
typedef float f32x16 __attribute__((ext_vector_type(16)));

__device__ __forceinline__ unsigned short f2bf(float f) {
    return __builtin_bit_cast(unsigned short, (__bf16)f);
}

__device__ __forceinline__ float bf2f(unsigned short u) {
    unsigned int x = ((unsigned int)u) << 16;
    return __builtin_bit_cast(float, x);
}

__device__ __forceinline__ unsigned int packbf2(float a, float b) {
    unsigned short lo = f2bf(a), hi = f2bf(b);
    return (unsigned int)lo | ((unsigned int)hi << 16);
}

__device__ __forceinline__ bf16x8 load_frag(const unsigned short* p) {
    int4 v = *reinterpret_cast<const int4*>(p);
    return __builtin_bit_cast(bf16x8, v);
}

__device__ __forceinline__ void gload_lds16(const unsigned short* g, unsigned short* l) {
    __builtin_amdgcn_global_load_lds((const __attribute__((address_space(1))) void*)g,
                                     (__attribute__((address_space(3))) void*)l, 16, 0, 0);
}

// ---------- prep: x + 4 weights -> bf16 (4 elems/thread); tail blocks build rope table ----------
__global__ __launch_bounds__(256) void prep_bf16(const float* __restrict__ x,
                                                 const float* __restrict__ wq,
                                                 const float* __restrict__ wk,
                                                 const float* __restrict__ wv,
                                                 const float* __restrict__ wp,
                                                 unsigned short* __restrict__ xb,
                                                 unsigned short* __restrict__ wall,
                                                 float* __restrict__ cost,
                                                 float* __restrict__ sint) {
    int bid = blockIdx.x;
    if (bid < 8192) {
        int i = (bid * 256 + threadIdx.x) * 4;            // 0..8M-4
        const float* src;
        unsigned short* dst;
        int soff, doff;
        if (i < (1 << 22)) {                               // x: 4M elems
            src = x; dst = xb; soff = i; doff = i;
        } else {
            int j = i - (1 << 22);                         // weights: 4x 1M elems
            int r = j >> 20;
            src = (r == 0) ? wq : ((r == 1) ? wk : ((r == 2) ? wv : wp));
            dst = wall; soff = j & 1048575; doff = j;
        }
        float4 v = *reinterpret_cast<const float4*>(&src[soff]);
        unsigned short tmp[4] = {f2bf(v.x), f2bf(v.y), f2bf(v.z), f2bf(v.w)};
        *reinterpret_cast<int2*>(&dst[doff]) = *reinterpret_cast<int2*>(tmp);
    } else {
        int i = (bid - 8192) * 256 + threadIdx.x;          // 2048*32
        int t = i >> 5, d = i & 31;
        float inv = powf(10000.0f, -(float)d / 32.0f);
        float f = (float)t * inv;
        cost[i] = cosf(f);
        sint[i] = sinf(f);
    }
}

// ---------- Q/K GEMM with fused rmsnorm+rope epilogue (grid 32 x 16) ----------
__global__ __launch_bounds__(256) void gemm_qk(const unsigned short* __restrict__ A,
                                               const unsigned short* __restrict__ B,
                                               const float* __restrict__ cost,
                                               const float* __restrict__ sint,
                                               unsigned short* __restrict__ qb,
                                               unsigned short* __restrict__ kb) {
    __shared__ __align__(16) unsigned short As[128 * 64];
    __shared__ __align__(16) unsigned short Bs[128 * 64];
    int tid = threadIdx.x;
    int lane = tid & 63;
    int w = tid >> 6;
    int wm = w >> 1, wn = w & 1;
    int m0 = blockIdx.x * 128;
    int n0 = blockIdx.y * 128;

    f32x4 acc[4][4] = {};

    int r8 = lane >> 3;
    int csrc = (lane & 7) ^ r8;      // pre-swizzled source 16B-unit (involution)

    for (int k0 = 0; k0 < 1024; k0 += 64) {
        __syncthreads();
#pragma unroll
        for (int c = 0; c < 4; ++c) {
            int row = 32 * w + 8 * c + r8;
            gload_lds16(&A[(size_t)(m0 + row) * 1024 + k0 + csrc * 8], &As[(32 * w + 8 * c) * 64]);
            gload_lds16(&B[(size_t)(n0 + row) * 1024 + k0 + csrc * 8], &Bs[(32 * w + 8 * c) * 64]);
        }
        __syncthreads();
#pragma unroll
        for (int kk = 0; kk < 2; ++kk) {
            int col16 = kk * 4 + (lane >> 4);
            bf16x8 af[4], bfr[4];
#pragma unroll
            for (int i = 0; i < 4; ++i) {
                int row = wm * 64 + i * 16 + (lane & 15);
                af[i] = load_frag(&As[row * 64 + (col16 ^ (row & 7)) * 8]);
            }
#pragma unroll
            for (int j = 0; j < 4; ++j) {
                int row = wn * 64 + j * 16 + (lane & 15);
                bfr[j] = load_frag(&Bs[row * 64 + (col16 ^ (row & 7)) * 8]);
            }
#pragma unroll
            for (int i = 0; i < 4; ++i)
#pragma unroll
                for (int j = 0; j < 4; ++j)
                    acc[i][j] = __builtin_amdgcn_mfma_f32_16x16x32_bf16(af[i], bfr[j], acc[i][j], 0, 0, 0);
        }
    }

    int r0 = (lane >> 4) * 4;
    int cc = lane & 15;
    int sec = blockIdx.y >> 3;               // 0=q, 1=k
    int hh = (blockIdx.y & 7) * 2 + wn;      // head 0..15
    unsigned short* dst = (sec == 0) ? qb : kb;
    float sc = (sec == 0) ? (0.125f * 1.44269504088896f) : 1.0f;  // fold softmax scale + log2e into q
#pragma unroll
    for (int i = 0; i < 4; ++i)
#pragma unroll
        for (int r = 0; r < 4; ++r) {
            float ss = 0.0f;
#pragma unroll
            for (int j = 0; j < 4; ++j) ss += acc[i][j][r] * acc[i][j][r];
            ss += __shfl_xor(ss, 1, 64);
            ss += __shfl_xor(ss, 2, 64);
            ss += __shfl_xor(ss, 4, 64);
            ss += __shfl_xor(ss, 8, 64);
            float rn = rsqrtf(ss * (1.0f / 64.0f) + 1e-6f);
            int mm = m0 + wm * 64 + i * 16 + r0 + r;
            int t = mm & 2047, b = mm >> 11;
            size_t rowb = ((size_t)((b * 16 + hh) * 2048 + t)) * 64;
#pragma unroll
            for (int j = 0; j < 2; ++j) {
                int dm = j * 16 + cc;
                float c = cost[t * 32 + dm], s_ = sint[t * 32 + dm];
                float x1 = acc[i][j][r] * rn;
                float x2 = acc[i][j + 2][r] * rn;
                dst[rowb + dm]      = f2bf((x1 * c + x2 * s_) * sc);
                dst[rowb + 32 + dm] = f2bf((x2 * c - x1 * s_) * sc);
            }
        }
}

// ---------- V GEMM with fused lerp + v1-passthrough + in-LDS transpose (grid 32 x 8) ----------
__global__ __launch_bounds__(256) void gemm_v(const unsigned short* __restrict__ A,
                                              const unsigned short* __restrict__ Bv,  // wv rows
                                              const float* __restrict__ v1,
                                              const float* __restrict__ lamb_p,
                                              unsigned short* __restrict__ vt,
                                              float* __restrict__ outv1) {
    __shared__ __align__(16) unsigned short smem[2 * 128 * 72];   // 36864B; As/Bs alias front 32KB
    unsigned short* As = smem;
    unsigned short* Bs = smem + 128 * 64;
    int tid = threadIdx.x;
    int lane = tid & 63;
    int w = tid >> 6;
    int wm = w >> 1, wn = w & 1;
    int m0 = blockIdx.x * 128;
    int n0 = blockIdx.y * 128;

    f32x4 acc[4][4] = {};

    int r8 = lane >> 3;
    int csrc = (lane & 7) ^ r8;

    for (int k0 = 0; k0 < 1024; k0 += 64) {
        __syncthreads();
#pragma unroll
        for (int c = 0; c < 4; ++c) {
            int row = 32 * w + 8 * c + r8;
            gload_lds16(&A[(size_t)(m0 + row) * 1024 + k0 + csrc * 8], &As[(32 * w + 8 * c) * 64]);
            gload_lds16(&Bv[(size_t)(n0 + row) * 1024 + k0 + csrc * 8], &Bs[(32 * w + 8 * c) * 64]);
        }
        __syncthreads();
#pragma unroll
        for (int kk = 0; kk < 2; ++kk) {
            int col16 = kk * 4 + (lane >> 4);
            bf16x8 af[4], bfr[4];
#pragma unroll
            for (int i = 0; i < 4; ++i) {
                int row = wm * 64 + i * 16 + (lane & 15);
                af[i] = load_frag(&As[row * 64 + (col16 ^ (row & 7)) * 8]);
            }
#pragma unroll
            for (int j = 0; j < 4; ++j) {
                int row = wn * 64 + j * 16 + (lane & 15);
                bfr[j] = load_frag(&Bs[row * 64 + (col16 ^ (row & 7)) * 8]);
            }
#pragma unroll
            for (int i = 0; i < 4; ++i)
#pragma unroll
                for (int j = 0; j < 4; ++j)
                    acc[i][j] = __builtin_amdgcn_mfma_f32_16x16x32_bf16(af[i], bfr[j], acc[i][j], 0, 0, 0);
        }
    }

    // lerp + v1 passthrough, write into per-head LDS tile [head][t_local 128][d 64 +pad 72]
    typedef unsigned short (*tile_t)[128][72];
    tile_t tile = reinterpret_cast<tile_t>(smem);
    int r0 = (lane >> 4) * 4;
    int cc = lane & 15;
    int hh = blockIdx.y * 2 + wn;            // head 0..15
    float lam = lamb_p[0];
    float oml = 1.0f - lam;
    __syncthreads();                         // As/Bs dead; safe to overlay
#pragma unroll
    for (int i = 0; i < 4; ++i)
#pragma unroll
        for (int r = 0; r < 4; ++r) {
            int tl = wm * 64 + i * 16 + r0 + r;      // 0..127
            int mm = m0 + tl;
            int t = mm & 2047, b = mm >> 11;
            size_t v1row = ((size_t)((b * 2048 + t) * 16 + hh)) * 64;
#pragma unroll
            for (int j = 0; j < 4; ++j) {
                int d = j * 16 + cc;
                float v1v = v1[v1row + d];
                outv1[v1row + d] = v1v;              // v1 passthrough output
                tile[wn][tl][d] = f2bf(oml * acc[i][j][r] + lam * v1v);
            }
        }
    __syncthreads();

    // transposed store: vt[bh][d][t0+..]
    int h2 = tid >> 7;                       // 0/1
    int idx = tid & 127;
    int rr2 = idx >> 2;                      // 0..31 -> d rows rr2, rr2+32
    int c2 = (idx & 3) * 8;                  // 0,8,16,24
    int hhs = blockIdx.y * 2 + h2;
    int t0 = m0 & 2047;
    int bb = m0 >> 11;
    unsigned short* dst = vt + ((size_t)(bb * 16 + hhs)) * 64 * 2048;
    unsigned short tmp[8];
#pragma unroll
    for (int tb = 0; tb < 128; tb += 32) {
#pragma unroll
        for (int j = 0; j < 8; ++j) tmp[j] = tile[h2][tb + c2 + j][rr2];
        *reinterpret_cast<int4*>(&dst[(size_t)rr2 * 2048 + t0 + tb + c2]) = *reinterpret_cast<int4*>(tmp);
#pragma unroll
        for (int j = 0; j < 8; ++j) tmp[j] = tile[h2][tb + c2 + j][rr2 + 32];
        *reinterpret_cast<int4*>(&dst[(size_t)(rr2 + 32) * 2048 + t0 + tb + c2]) = *reinterpret_cast<int4*>(tmp);
    }
}

// ---------- proj GEMM with fused kv-split combine on the A side (proven R14) ----------
__global__ __launch_bounds__(256) void gemm_proj(const unsigned short* __restrict__ pO,
                                                 const float* __restrict__ lsum,
                                                 const unsigned short* __restrict__ B,
                                                 float* __restrict__ C) {
    __shared__ __align__(16) unsigned short As[128 * 64];
    __shared__ __align__(16) unsigned short Bs[128 * 64];
    int tid = threadIdx.x;
    int lane = tid & 63;
    int w = tid >> 6;
    int wm = w >> 1, wn = w & 1;
    int m0 = blockIdx.x * 128;
    int n0 = blockIdx.y * 128;

    f32x4 acc[4][4] = {};

    int r8 = lane >> 3;
    int c8 = lane & 7;
    int csrc = c8 ^ r8;

    for (int k0 = 0; k0 < 1024; k0 += 64) {
        int h = k0 >> 6;
        __syncthreads();
#pragma unroll
        for (int c = 0; c < 4; ++c) {
            int row = 32 * w + 8 * c + r8;
            int m = m0 + row;
            int bh = ((m >> 11) << 4) + h;
            int qi = m & 2047;
            int li = bh * 2048 + qi;
            size_t pi = (size_t)li * 64 + csrc * 8;
            int4 p0 = *reinterpret_cast<const int4*>(&pO[pi]);
            int4 p1 = *reinterpret_cast<const int4*>(&pO[4194304u + pi]);
            float linv = 1.0f / (lsum[li] + lsum[65536 + li]);
            const unsigned short* u0 = reinterpret_cast<const unsigned short*>(&p0);
            const unsigned short* u1 = reinterpret_cast<const unsigned short*>(&p1);
            unsigned short tmp[8];
#pragma unroll
            for (int j = 0; j < 8; ++j) tmp[j] = f2bf((bf2f(u0[j]) + bf2f(u1[j])) * linv);
            *reinterpret_cast<int4*>(&As[row * 64 + c8 * 8]) = *reinterpret_cast<int4*>(tmp);
            gload_lds16(&B[(size_t)(n0 + row) * 1024 + k0 + csrc * 8], &Bs[(32 * w + 8 * c) * 64]);
        }
        __syncthreads();
#pragma unroll
        for (int kk = 0; kk < 2; ++kk) {
            int col16 = kk * 4 + (lane >> 4);
            bf16x8 af[4], bfr[4];
#pragma unroll
            for (int i = 0; i < 4; ++i) {
                int row = wm * 64 + i * 16 + (lane & 15);
                af[i] = load_frag(&As[row * 64 + (col16 ^ (row & 7)) * 8]);
            }
#pragma unroll
            for (int j = 0; j < 4; ++j) {
                int row = wn * 64 + j * 16 + (lane & 15);
                bfr[j] = load_frag(&Bs[row * 64 + (col16 ^ (row & 7)) * 8]);
            }
#pragma unroll
            for (int i = 0; i < 4; ++i)
#pragma unroll
                for (int j = 0; j < 4; ++j)
                    acc[i][j] = __builtin_amdgcn_mfma_f32_16x16x32_bf16(af[i], bfr[j], acc[i][j], 0, 0, 0);
        }
    }
    int r0 = (lane >> 4) * 4;
    int cc = lane & 15;
#pragma unroll
    for (int i = 0; i < 4; ++i)
#pragma unroll
        for (int j = 0; j < 4; ++j)
#pragma unroll
            for (int r = 0; r < 4; ++r) {
                size_t m = m0 + wm * 64 + i * 16 + r0 + r;
                size_t n = n0 + wn * 64 + j * 16 + cc;
                C[m * 1024 + n] = acc[i][j][r];
            }
}

// ---------- flash attention, kv-split x2, causal, swapped-QK^T 32x32 MFMA ----------
// R17 staging (gload_lds dbuf, 1 barrier/tile) + T5 s_setprio around MFMA clusters:
// 4 independent blocks/CU at different kt phases -> scheduler favors MFMA-entering waves.
__global__ __launch_bounds__(256) void attn(const unsigned short* __restrict__ qb,
                                            const unsigned short* __restrict__ kb,
                                            const unsigned short* __restrict__ vt,   // [bh][64][2048]
                                            unsigned short* __restrict__ pO,         // [ck][bh][2048][64] bf16
                                            float* __restrict__ lsum) {              // [ck][bh][2048] f32
    __shared__ __align__(16) unsigned short KsL[2][64 * 64];   // [buf][kv*d] linear
    __shared__ __align__(16) unsigned short VtL[2][64 * 64];   // [buf][d*kv] linear
    int tid = threadIdx.x;
    int lane = tid & 63;
    int w = tid >> 6;
    int hi = lane >> 5;
    int l31 = lane & 31;

    int bid = blockIdx.x;                    // 0..1023
    int bh = bid & 31;
    int r5 = bid >> 5;                       // 0..31
    int qt = 15 - (r5 >> 1);                 // heavy first
    int ck = r5 & 1;
    int q0 = qt * 128;
    const size_t base = (size_t)bh * 2048 * 64;
    const unsigned short* vtb = vt + (size_t)bh * 64 * 2048;
    int ktlo = ck * (qt + 1);
    int kthi = (ck + 1) * (qt + 1);          // exclusive

    bf16x8 qf[4];
    int qrow = q0 + w * 32 + l31;
#pragma unroll
    for (int kd = 0; kd < 4; ++kd)
        qf[kd] = load_frag(&qb[base + (size_t)qrow * 64 + kd * 16 + hi * 8]);

    f32x16 oacc[2] = {};
    float lrun = 0.0f;

    int rl = lane >> 3;              // 0..7
    int ul = lane & 7;
#define STAGE(pp, kt_)                                                                     \
    do {                                                                                   \
        _Pragma("unroll") for (int i2 = 0; i2 < 2; ++i2) {                                 \
            int rr = (w * 2 + i2) * 8 + rl;                                                \
            int cu = ul ^ (rr & 7);                                                        \
            gload_lds16(&kb[base + (size_t)((kt_) * 64 + rr) * 64 + cu * 8],               \
                        &KsL[pp][(w * 2 + i2) * 512]);                                     \
            gload_lds16(&vtb[(size_t)rr * 2048 + (kt_) * 64 + cu * 8],                     \
                        &VtL[pp][(w * 2 + i2) * 512]);                                     \
        }                                                                                  \
    } while (0)

    int qwlo = q0 + w * 32;
    int p = 0;
    STAGE(0, ktlo);
    __syncthreads();
    for (int kt = ktlo; kt < kthi; ++kt) {
        if (kt + 1 < kthi) STAGE(p ^ 1, kt + 1);

        if (kt * 64 <= qwlo + 31) {
            bool diag = (kt * 64 + 63 > qwlo);
            float rs01 = 0.0f, rs23 = 0.0f;
#pragma unroll
            for (int ntl = 0; ntl < 2; ++ntl) {
                // QK^T for this 32-kv half: m = kv, n = q
                f32x16 sacc = {};
                __builtin_amdgcn_s_setprio(1);
#pragma unroll
                for (int kd = 0; kd < 4; ++kd) {
                    int R = ntl * 32 + l31;
                    bf16x8 kf = load_frag(&KsL[p][R * 64 + (((kd << 1) | hi) ^ (R & 7)) * 8]);
                    sacc = __builtin_amdgcn_mfma_f32_32x32x16_bf16(kf, qf[kd], sacc, 0, 0, 0);
                }
                __builtin_amdgcn_s_setprio(0);

#pragma unroll
                for (int r = 0; r < 16; ++r) {
                    float s = sacc[r];
                    if (diag) {
                        int kvg = kt * 64 + ntl * 32 + (r & 3) + 8 * (r >> 2) + 4 * hi;
                        if (kvg > qrow) s = -3.0e38f;
                    }
                    float e = __builtin_amdgcn_exp2f(s);
                    sacc[r] = e;
                    if (r & 2) rs23 += e; else rs01 += e;
                }

                unsigned int wAa[4], wBb[4];
#pragma unroll
                for (int rr = 0; rr < 4; ++rr) {
                    wAa[rr] = packbf2(sacc[4 * rr + 0], sacc[4 * rr + 1]);
                    wBb[rr] = packbf2(sacc[4 * rr + 2], sacc[4 * rr + 3]);
                }

                // PV for this half: 2 k-slices of 16 kv; A-frag via permlane32_swap
                __builtin_amdgcn_s_setprio(1);
#pragma unroll
                for (int ks2 = 0; ks2 < 2; ++ks2) {
                    int b2 = ks2 * 2;
                    auto rA = __builtin_amdgcn_permlane32_swap(wAa[b2], wAa[b2 + 1], false, false);
                    auto rB = __builtin_amdgcn_permlane32_swap(wBb[b2], wBb[b2 + 1], false, false);
                    uint4 pa;
                    pa.x = rA[0];   // kv 16ks+8hi+{0,1}
                    pa.y = rB[0];   // +{2,3}
                    pa.z = rA[1];   // +{4,5}
                    pa.w = rB[1];   // +{6,7}
                    bf16x8 paf = __builtin_bit_cast(bf16x8, pa);
                    int ks = ntl * 2 + ks2;
#pragma unroll
                    for (int dt = 0; dt < 2; ++dt) {
                        int R2 = dt * 32 + l31;
                        bf16x8 vtf = load_frag(&VtL[p][R2 * 64 + (((ks << 1) | hi) ^ (R2 & 7)) * 8]);
                        oacc[dt] = __builtin_amdgcn_mfma_f32_32x32x16_bf16(paf, vtf, oacc[dt], 0, 0, 0);
                    }
                }
                __builtin_amdgcn_s_setprio(0);
            }
            float rs = rs01 + rs23;
            rs += __shfl_xor(rs, 32, 64);
            lrun += rs;
        }
        __syncthreads();   // drains staged gloads (vmcnt 0) + protects buf p for overwrite
        p ^= 1;
    }

    unsigned short* po = pO + ((size_t)ck * 4194304u);
    float* ls = lsum + ck * 65536;
#pragma unroll
    for (int r = 0; r < 16; ++r) {
        int ql = (r & 3) + 8 * (r >> 2) + 4 * hi;
        int q = q0 + w * 32 + ql;
        size_t ro = ((size_t)bh * 2048 + q) * 64;
        po[ro + l31]      = f2bf(oacc[0][r]);
        po[ro + 32 + l31] = f2bf(oacc[1][r]);
    }
    if (hi == 0) ls[bh * 2048 + q0 + w * 32 + l31] = lrun;
#undef STAGE
}

// ---------- launch ----------
extern "C" void kernel_launch(void* const* d_in, const int* in_sizes, int n_in,
                              void* d_out, int out_size, void* d_ws, size_t ws_size,
                              hipStream_t stream) {
    const float* x      = (const float*)d_in[0];   // [2,2048,1024]
    const float* v1     = (const float*)d_in[1];   // [2,2048,16,64]
    const float* w_q    = (const float*)d_in[2];
    const float* w_k    = (const float*)d_in[3];
    const float* w_v    = (const float*)d_in[4];
    const float* w_proj = (const float*)d_in[5];
    const float* lamb   = (const float*)d_in[6];
    float* out = (float*)d_out;

    char* ws = (char*)d_ws;
    unsigned short* xb      = (unsigned short*)(ws + 0);           // 8MB
    unsigned short* wall_b  = (unsigned short*)(ws + (8u  << 20)); // 8MB: [wq|wk|wv|wproj]
    unsigned short* wqkv_b  = wall_b;
    unsigned short* wv_b    = wall_b + 2u * 1048576u;
    unsigned short* wproj_b = wall_b + 3u * 1048576u;
    unsigned short* vtp     = (unsigned short*)(ws + (40u << 20)); // 8MB [bh][64][2048]
    unsigned short* qbuf    = (unsigned short*)(ws + (48u << 20)); // 8MB
    unsigned short* kbuf    = (unsigned short*)(ws + (56u << 20)); // 8MB
    float*          cost    = (float*)        (ws + (72u << 20));
    float*          sint    = (float*)        (ws + (72u << 20) + 262144);
    unsigned short* pO      = (unsigned short*)(ws + (80u << 20)); // 2 x 8MB partials (stride 4194304 elems)
    float*          lsum    = (float*)        (ws + (112u << 20)); // 2 x 256KB

    prep_bf16<<<8448, 256, 0, stream>>>(x, w_q, w_k, w_v, w_proj, xb, wall_b, cost, sint);

    gemm_qk<<<dim3(32, 16), 256, 0, stream>>>(xb, wqkv_b, cost, sint, qbuf, kbuf);
    gemm_v<<<dim3(32, 8), 256, 0, stream>>>(xb, wv_b, v1, lamb, vtp, out + 4194304);

    attn<<<1024, 256, 0, stream>>>(qbuf, kbuf, vtp, pO, lsum);

    gemm_proj<<<dim3(32, 8), 256, 0, stream>>>(pO, lsum, wproj_b, out);
}

// Round 19
// 130.476 us; speedup vs baseline: 1.0062x; 1.0062x over previous
//
#include <hip/hip_runtime.h>

// ---------- types ----------
typedef __bf16 bf16x8 __attribute__((ext_vector_type(8)));
typedef float f32x4 __attribute__((ext_vector_type(4)));
typedef float f32x16 __attribute__((ext_vector_type(16)));

__device__ __forceinline__ unsigned short f2bf(float f) {
    return __builtin_bit_cast(unsigned short, (__bf16)f);
}

__device__ __forceinline__ float bf2f(unsigned short u) {
    unsigned int x = ((unsigned int)u) << 16;
    return __builtin_bit_cast(float, x);
}

__device__ __forceinline__ unsigned int packbf2(float a, float b) {
    unsigned short lo = f2bf(a), hi = f2bf(b);
    return (unsigned int)lo | ((unsigned int)hi << 16);
}

__device__ __forceinline__ bf16x8 load_frag(const unsigned short* p) {
    int4 v = *reinterpret_cast<const int4*>(p);
    return __builtin_bit_cast(bf16x8, v);
}

__device__ __forceinline__ void gload_lds16(const unsigned short* g, unsigned short* l) {
    __builtin_amdgcn_global_load_lds((const __attribute__((address_space(1))) void*)g,
                                     (__attribute__((address_space(3))) void*)l, 16, 0, 0);
}

// ---------- prep: x + 4 weights -> bf16 (4 elems/thread); tail blocks build rope table ----------
__global__ __launch_bounds__(256) void prep_bf16(const float* __restrict__ x,
                                                 const float* __restrict__ wq,
                                                 const float* __restrict__ wk,
                                                 const float* __restrict__ wv,
                                                 const float* __restrict__ wp,
                                                 unsigned short* __restrict__ xb,
                                                 unsigned short* __restrict__ wall,
                                                 float* __restrict__ cost,
                                                 float* __restrict__ sint) {
    int bid = blockIdx.x;
    if (bid < 8192) {
        int i = (bid * 256 + threadIdx.x) * 4;            // 0..8M-4
        const float* src;
        unsigned short* dst;
        int soff, doff;
        if (i < (1 << 22)) {                               // x: 4M elems
            src = x; dst = xb; soff = i; doff = i;
        } else {
            int j = i - (1 << 22);                         // weights: 4x 1M elems
            int r = j >> 20;
            src = (r == 0) ? wq : ((r == 1) ? wk : ((r == 2) ? wv : wp));
            dst = wall; soff = j & 1048575; doff = j;
        }
        float4 v = *reinterpret_cast<const float4*>(&src[soff]);
        unsigned short tmp[4] = {f2bf(v.x), f2bf(v.y), f2bf(v.z), f2bf(v.w)};
        *reinterpret_cast<int2*>(&dst[doff]) = *reinterpret_cast<int2*>(tmp);
    } else {
        int i = (bid - 8192) * 256 + threadIdx.x;          // 2048*32
        int t = i >> 5, d = i & 31;
        float inv = powf(10000.0f, -(float)d / 32.0f);
        float f = (float)t * inv;
        cost[i] = cosf(f);
        sint[i] = sinf(f);
    }
}

// ---------- Q/K GEMM with fused rmsnorm+rope epilogue (grid 32 x 16) ----------
__global__ __launch_bounds__(256) void gemm_qk(const unsigned short* __restrict__ A,
                                               const unsigned short* __restrict__ B,
                                               const float* __restrict__ cost,
                                               const float* __restrict__ sint,
                                               unsigned short* __restrict__ qb,
                                               unsigned short* __restrict__ kb) {
    __shared__ __align__(16) unsigned short As[128 * 64];
    __shared__ __align__(16) unsigned short Bs[128 * 64];
    int tid = threadIdx.x;
    int lane = tid & 63;
    int w = tid >> 6;
    int wm = w >> 1, wn = w & 1;
    int m0 = blockIdx.x * 128;
    int n0 = blockIdx.y * 128;

    f32x4 acc[4][4] = {};

    int r8 = lane >> 3;
    int csrc = (lane & 7) ^ r8;      // pre-swizzled source 16B-unit (involution)

    for (int k0 = 0; k0 < 1024; k0 += 64) {
        __syncthreads();
#pragma unroll
        for (int c = 0; c < 4; ++c) {
            int row = 32 * w + 8 * c + r8;
            gload_lds16(&A[(size_t)(m0 + row) * 1024 + k0 + csrc * 8], &As[(32 * w + 8 * c) * 64]);
            gload_lds16(&B[(size_t)(n0 + row) * 1024 + k0 + csrc * 8], &Bs[(32 * w + 8 * c) * 64]);
        }
        __syncthreads();
#pragma unroll
        for (int kk = 0; kk < 2; ++kk) {
            int col16 = kk * 4 + (lane >> 4);
            bf16x8 af[4], bfr[4];
#pragma unroll
            for (int i = 0; i < 4; ++i) {
                int row = wm * 64 + i * 16 + (lane & 15);
                af[i] = load_frag(&As[row * 64 + (col16 ^ (row & 7)) * 8]);
            }
#pragma unroll
            for (int j = 0; j < 4; ++j) {
                int row = wn * 64 + j * 16 + (lane & 15);
                bfr[j] = load_frag(&Bs[row * 64 + (col16 ^ (row & 7)) * 8]);
            }
#pragma unroll
            for (int i = 0; i < 4; ++i)
#pragma unroll
                for (int j = 0; j < 4; ++j)
                    acc[i][j] = __builtin_amdgcn_mfma_f32_16x16x32_bf16(af[i], bfr[j], acc[i][j], 0, 0, 0);
        }
    }

    int r0 = (lane >> 4) * 4;
    int cc = lane & 15;
    int sec = blockIdx.y >> 3;               // 0=q, 1=k
    int hh = (blockIdx.y & 7) * 2 + wn;      // head 0..15
    unsigned short* dst = (sec == 0) ? qb : kb;
    float sc = (sec == 0) ? (0.125f * 1.44269504088896f) : 1.0f;  // fold softmax scale + log2e into q
#pragma unroll
    for (int i = 0; i < 4; ++i)
#pragma unroll
        for (int r = 0; r < 4; ++r) {
            float ss = 0.0f;
#pragma unroll
            for (int j = 0; j < 4; ++j) ss += acc[i][j][r] * acc[i][j][r];
            ss += __shfl_xor(ss, 1, 64);
            ss += __shfl_xor(ss, 2, 64);
            ss += __shfl_xor(ss, 4, 64);
            ss += __shfl_xor(ss, 8, 64);
            float rn = rsqrtf(ss * (1.0f / 64.0f) + 1e-6f);
            int mm = m0 + wm * 64 + i * 16 + r0 + r;
            int t = mm & 2047, b = mm >> 11;
            size_t rowb = ((size_t)((b * 16 + hh) * 2048 + t)) * 64;
#pragma unroll
            for (int j = 0; j < 2; ++j) {
                int dm = j * 16 + cc;
                float c = cost[t * 32 + dm], s_ = sint[t * 32 + dm];
                float x1 = acc[i][j][r] * rn;
                float x2 = acc[i][j + 2][r] * rn;
                dst[rowb + dm]      = f2bf((x1 * c + x2 * s_) * sc);
                dst[rowb + 32 + dm] = f2bf((x2 * c - x1 * s_) * sc);
            }
        }
}

// ---------- V GEMM with fused lerp + v1-passthrough + in-LDS transpose (grid 32 x 8) ----------
__global__ __launch_bounds__(256) void gemm_v(const unsigned short* __restrict__ A,
                                              const unsigned short* __restrict__ Bv,  // wv rows
                                              const float* __restrict__ v1,
                                              const float* __restrict__ lamb_p,
                                              unsigned short* __restrict__ vt,
                                              float* __restrict__ outv1) {
    __shared__ __align__(16) unsigned short smem[2 * 128 * 72];   // 36864B; As/Bs alias front 32KB
    unsigned short* As = smem;
    unsigned short* Bs = smem + 128 * 64;
    int tid = threadIdx.x;
    int lane = tid & 63;
    int w = tid >> 6;
    int wm = w >> 1, wn = w & 1;
    int m0 = blockIdx.x * 128;
    int n0 = blockIdx.y * 128;

    f32x4 acc[4][4] = {};

    int r8 = lane >> 3;
    int csrc = (lane & 7) ^ r8;

    for (int k0 = 0; k0 < 1024; k0 += 64) {
        __syncthreads();
#pragma unroll
        for (int c = 0; c < 4; ++c) {
            int row = 32 * w + 8 * c + r8;
            gload_lds16(&A[(size_t)(m0 + row) * 1024 + k0 + csrc * 8], &As[(32 * w + 8 * c) * 64]);
            gload_lds16(&Bv[(size_t)(n0 + row) * 1024 + k0 + csrc * 8], &Bs[(32 * w + 8 * c) * 64]);
        }
        __syncthreads();
#pragma unroll
        for (int kk = 0; kk < 2; ++kk) {
            int col16 = kk * 4 + (lane >> 4);
            bf16x8 af[4], bfr[4];
#pragma unroll
            for (int i = 0; i < 4; ++i) {
                int row = wm * 64 + i * 16 + (lane & 15);
                af[i] = load_frag(&As[row * 64 + (col16 ^ (row & 7)) * 8]);
            }
#pragma unroll
            for (int j = 0; j < 4; ++j) {
                int row = wn * 64 + j * 16 + (lane & 15);
                bfr[j] = load_frag(&Bs[row * 64 + (col16 ^ (row & 7)) * 8]);
            }
#pragma unroll
            for (int i = 0; i < 4; ++i)
#pragma unroll
                for (int j = 0; j < 4; ++j)
                    acc[i][j] = __builtin_amdgcn_mfma_f32_16x16x32_bf16(af[i], bfr[j], acc[i][j], 0, 0, 0);
        }
    }

    // lerp + v1 passthrough, write into per-head LDS tile [head][t_local 128][d 64 +pad 72]
    typedef unsigned short (*tile_t)[128][72];
    tile_t tile = reinterpret_cast<tile_t>(smem);
    int r0 = (lane >> 4) * 4;
    int cc = lane & 15;
    int hh = blockIdx.y * 2 + wn;            // head 0..15
    float lam = lamb_p[0];
    float oml = 1.0f - lam;
    __syncthreads();                         // As/Bs dead; safe to overlay
#pragma unroll
    for (int i = 0; i < 4; ++i)
#pragma unroll
        for (int r = 0; r < 4; ++r) {
            int tl = wm * 64 + i * 16 + r0 + r;      // 0..127
            int mm = m0 + tl;
            int t = mm & 2047, b = mm >> 11;
            size_t v1row = ((size_t)((b * 2048 + t) * 16 + hh)) * 64;
#pragma unroll
            for (int j = 0; j < 4; ++j) {
                int d = j * 16 + cc;
                float v1v = v1[v1row + d];
                outv1[v1row + d] = v1v;              // v1 passthrough output
                tile[wn][tl][d] = f2bf(oml * acc[i][j][r] + lam * v1v);
            }
        }
    __syncthreads();

    // transposed store: vt[bh][d][t0+..]
    int h2 = tid >> 7;                       // 0/1
    int idx = tid & 127;
    int rr2 = idx >> 2;                      // 0..31 -> d rows rr2, rr2+32
    int c2 = (idx & 3) * 8;                  // 0,8,16,24
    int hhs = blockIdx.y * 2 + h2;
    int t0 = m0 & 2047;
    int bb = m0 >> 11;
    unsigned short* dst = vt + ((size_t)(bb * 16 + hhs)) * 64 * 2048;
    unsigned short tmp[8];
#pragma unroll
    for (int tb = 0; tb < 128; tb += 32) {
#pragma unroll
        for (int j = 0; j < 8; ++j) tmp[j] = tile[h2][tb + c2 + j][rr2];
        *reinterpret_cast<int4*>(&dst[(size_t)rr2 * 2048 + t0 + tb + c2]) = *reinterpret_cast<int4*>(tmp);
#pragma unroll
        for (int j = 0; j < 8; ++j) tmp[j] = tile[h2][tb + c2 + j][rr2 + 32];
        *reinterpret_cast<int4*>(&dst[(size_t)(rr2 + 32) * 2048 + t0 + tb + c2]) = *reinterpret_cast<int4*>(tmp);
    }
}

// ---------- proj GEMM with fused kv-split combine on the A side (proven R14) ----------
__global__ __launch_bounds__(256) void gemm_proj(const unsigned short* __restrict__ pO,
                                                 const float* __restrict__ lsum,
                                                 const unsigned short* __restrict__ B,
                                                 float* __restrict__ C) {
    __shared__ __align__(16) unsigned short As[128 * 64];
    __shared__ __align__(16) unsigned short Bs[128 * 64];
    int tid = threadIdx.x;
    int lane = tid & 63;
    int w = tid >> 6;
    int wm = w >> 1, wn = w & 1;
    int m0 = blockIdx.x * 128;
    int n0 = blockIdx.y * 128;

    f32x4 acc[4][4] = {};

    int r8 = lane >> 3;
    int c8 = lane & 7;
    int csrc = c8 ^ r8;

    for (int k0 = 0; k0 < 1024; k0 += 64) {
        int h = k0 >> 6;
        __syncthreads();
#pragma unroll
        for (int c = 0; c < 4; ++c) {
            int row = 32 * w + 8 * c + r8;
            int m = m0 + row;
            int bh = ((m >> 11) << 4) + h;
            int qi = m & 2047;
            int li = bh * 2048 + qi;
            size_t pi = (size_t)li * 64 + csrc * 8;
            int4 p0 = *reinterpret_cast<const int4*>(&pO[pi]);
            int4 p1 = *reinterpret_cast<const int4*>(&pO[4194304u + pi]);
            float linv = 1.0f / (lsum[li] + lsum[65536 + li]);
            const unsigned short* u0 = reinterpret_cast<const unsigned short*>(&p0);
            const unsigned short* u1 = reinterpret_cast<const unsigned short*>(&p1);
            unsigned short tmp[8];
#pragma unroll
            for (int j = 0; j < 8; ++j) tmp[j] = f2bf((bf2f(u0[j]) + bf2f(u1[j])) * linv);
            *reinterpret_cast<int4*>(&As[row * 64 + c8 * 8]) = *reinterpret_cast<int4*>(tmp);
            gload_lds16(&B[(size_t)(n0 + row) * 1024 + k0 + csrc * 8], &Bs[(32 * w + 8 * c) * 64]);
        }
        __syncthreads();
#pragma unroll
        for (int kk = 0; kk < 2; ++kk) {
            int col16 = kk * 4 + (lane >> 4);
            bf16x8 af[4], bfr[4];
#pragma unroll
            for (int i = 0; i < 4; ++i) {
                int row = wm * 64 + i * 16 + (lane & 15);
                af[i] = load_frag(&As[row * 64 + (col16 ^ (row & 7)) * 8]);
            }
#pragma unroll
            for (int j = 0; j < 4; ++j) {
                int row = wn * 64 + j * 16 + (lane & 15);
                bfr[j] = load_frag(&Bs[row * 64 + (col16 ^ (row & 7)) * 8]);
            }
#pragma unroll
            for (int i = 0; i < 4; ++i)
#pragma unroll
                for (int j = 0; j < 4; ++j)
                    acc[i][j] = __builtin_amdgcn_mfma_f32_16x16x32_bf16(af[i], bfr[j], acc[i][j], 0, 0, 0);
        }
    }
    int r0 = (lane >> 4) * 4;
    int cc = lane & 15;
#pragma unroll
    for (int i = 0; i < 4; ++i)
#pragma unroll
        for (int j = 0; j < 4; ++j)
#pragma unroll
            for (int r = 0; r < 4; ++r) {
                size_t m = m0 + wm * 64 + i * 16 + r0 + r;
                size_t n = n0 + wn * 64 + j * 16 + cc;
                C[m * 1024 + n] = acc[i][j][r];
            }
}

// ---------- flash attention, kv-split x2, causal, swapped-QK^T 32x32 MFMA ----------
// R19: 4-buffer pair-wise pipeline — stage a PAIR of kv-tiles, compute TWO tiles
// (~1060 cyc) before the vmcnt drain at the barrier -> full L2-latency coverage,
// 0.5 barriers/tile. No setprio (R18 regression). Same math as R13-R18.
__global__ __launch_bounds__(256) void attn(const unsigned short* __restrict__ qb,
                                            const unsigned short* __restrict__ kb,
                                            const unsigned short* __restrict__ vt,   // [bh][64][2048]
                                            unsigned short* __restrict__ pO,         // [ck][bh][2048][64] bf16
                                            float* __restrict__ lsum) {              // [ck][bh][2048] f32
    __shared__ __align__(16) unsigned short KsL[4][64 * 64];   // [buf][kv*d] linear
    __shared__ __align__(16) unsigned short VtL[4][64 * 64];   // [buf][d*kv] linear
    int tid = threadIdx.x;
    int lane = tid & 63;
    int w = tid >> 6;
    int hi = lane >> 5;
    int l31 = lane & 31;

    int bid = blockIdx.x;                    // 0..1023
    int bh = bid & 31;
    int r5 = bid >> 5;                       // 0..31
    int qt = 15 - (r5 >> 1);                 // heavy first
    int ck = r5 & 1;
    int q0 = qt * 128;
    const size_t base = (size_t)bh * 2048 * 64;
    const unsigned short* vtb = vt + (size_t)bh * 64 * 2048;
    int ktlo = ck * (qt + 1);
    int kthi = (ck + 1) * (qt + 1);          // exclusive

    bf16x8 qf[4];
    int qrow = q0 + w * 32 + l31;
#pragma unroll
    for (int kd = 0; kd < 4; ++kd)
        qf[kd] = load_frag(&qb[base + (size_t)qrow * 64 + kd * 16 + hi * 8]);

    f32x16 oacc[2] = {};
    float lrun = 0.0f;

    int rl = lane >> 3;              // 0..7
    int ul = lane & 7;
#define STAGE(pp, kt_)                                                                     \
    do {                                                                                   \
        _Pragma("unroll") for (int i2 = 0; i2 < 2; ++i2) {                                 \
            int rr = (w * 2 + i2) * 8 + rl;                                                \
            int cu = ul ^ (rr & 7);                                                        \
            gload_lds16(&kb[base + (size_t)((kt_) * 64 + rr) * 64 + cu * 8],               \
                        &KsL[pp][(w * 2 + i2) * 512]);                                     \
            gload_lds16(&vtb[(size_t)rr * 2048 + (kt_) * 64 + cu * 8],                     \
                        &VtL[pp][(w * 2 + i2) * 512]);                                     \
        }                                                                                  \
    } while (0)

    int qwlo = q0 + w * 32;

    auto compute_tile = [&](int p, int kt) {
        if (kt * 64 > qwlo + 31) return;
        bool diag = (kt * 64 + 63 > qwlo);
        float rs01 = 0.0f, rs23 = 0.0f;
#pragma unroll
        for (int ntl = 0; ntl < 2; ++ntl) {
            // QK^T for this 32-kv half: m = kv, n = q
            f32x16 sacc = {};
#pragma unroll
            for (int kd = 0; kd < 4; ++kd) {
                int R = ntl * 32 + l31;
                bf16x8 kf = load_frag(&KsL[p][R * 64 + (((kd << 1) | hi) ^ (R & 7)) * 8]);
                sacc = __builtin_amdgcn_mfma_f32_32x32x16_bf16(kf, qf[kd], sacc, 0, 0, 0);
            }

#pragma unroll
            for (int r = 0; r < 16; ++r) {
                float s = sacc[r];
                if (diag) {
                    int kvg = kt * 64 + ntl * 32 + (r & 3) + 8 * (r >> 2) + 4 * hi;
                    if (kvg > qrow) s = -3.0e38f;
                }
                float e = __builtin_amdgcn_exp2f(s);
                sacc[r] = e;
                if (r & 2) rs23 += e; else rs01 += e;
            }

            unsigned int wAa[4], wBb[4];
#pragma unroll
            for (int rr = 0; rr < 4; ++rr) {
                wAa[rr] = packbf2(sacc[4 * rr + 0], sacc[4 * rr + 1]);
                wBb[rr] = packbf2(sacc[4 * rr + 2], sacc[4 * rr + 3]);
            }

            // PV for this half: 2 k-slices of 16 kv; A-frag via permlane32_swap
#pragma unroll
            for (int ks2 = 0; ks2 < 2; ++ks2) {
                int b2 = ks2 * 2;
                auto rA = __builtin_amdgcn_permlane32_swap(wAa[b2], wAa[b2 + 1], false, false);
                auto rB = __builtin_amdgcn_permlane32_swap(wBb[b2], wBb[b2 + 1], false, false);
                uint4 pa;
                pa.x = rA[0];   // kv 16ks+8hi+{0,1}
                pa.y = rB[0];   // +{2,3}
                pa.z = rA[1];   // +{4,5}
                pa.w = rB[1];   // +{6,7}
                bf16x8 paf = __builtin_bit_cast(bf16x8, pa);
                int ks = ntl * 2 + ks2;
#pragma unroll
                for (int dt = 0; dt < 2; ++dt) {
                    int R2 = dt * 32 + l31;
                    bf16x8 vtf = load_frag(&VtL[p][R2 * 64 + (((ks << 1) | hi) ^ (R2 & 7)) * 8]);
                    oacc[dt] = __builtin_amdgcn_mfma_f32_32x32x16_bf16(paf, vtf, oacc[dt], 0, 0, 0);
                }
            }
        }
        float rs = rs01 + rs23;
        rs += __shfl_xor(rs, 32, 64);
        lrun += rs;
    };

    // prologue: stage first pair
    STAGE(0, ktlo);
    if (ktlo + 1 < kthi) STAGE(1, ktlo + 1);
    __syncthreads();

    int pb = 0;
    for (int kt2 = ktlo; kt2 < kthi; kt2 += 2) {
        // issue next pair's DMA before computing current pair (2-tile latency coverage)
        if (kt2 + 2 < kthi) STAGE(pb ^ 2, kt2 + 2);
        if (kt2 + 3 < kthi) STAGE((pb ^ 2) | 1, kt2 + 3);

        compute_tile(pb, kt2);
        if (kt2 + 1 < kthi) compute_tile(pb | 1, kt2 + 1);

        __syncthreads();   // drains staged DMA (vmcnt 0) + protects pair pb for overwrite
        pb ^= 2;
    }

    unsigned short* po = pO + ((size_t)ck * 4194304u);
    float* ls = lsum + ck * 65536;
#pragma unroll
    for (int r = 0; r < 16; ++r) {
        int ql = (r & 3) + 8 * (r >> 2) + 4 * hi;
        int q = q0 + w * 32 + ql;
        size_t ro = ((size_t)bh * 2048 + q) * 64;
        po[ro + l31]      = f2bf(oacc[0][r]);
        po[ro + 32 + l31] = f2bf(oacc[1][r]);
    }
    if (hi == 0) ls[bh * 2048 + q0 + w * 32 + l31] = lrun;
#undef STAGE
}

// ---------- launch ----------
extern "C" void kernel_launch(void* const* d_in, const int* in_sizes, int n_in,
                              void* d_out, int out_size, void* d_ws, size_t ws_size,
                              hipStream_t stream) {
    const float* x      = (const float*)d_in[0];   // [2,2048,1024]
    const float* v1     = (const float*)d_in[1];   // [2,2048,16,64]
    const float* w_q    = (const float*)d_in[2];
    const float* w_k    = (const float*)d_in[3];
    const float* w_v    = (const float*)d_in[4];
    const float* w_proj = (const float*)d_in[5];
    const float* lamb   = (const float*)d_in[6];
    float* out = (float*)d_out;

    char* ws = (char*)d_ws;
    unsigned short* xb      = (unsigned short*)(ws + 0);           // 8MB
    unsigned short* wall_b  = (unsigned short*)(ws + (8u  << 20)); // 8MB: [wq|wk|wv|wproj]
    unsigned short* wqkv_b  = wall_b;
    unsigned short* wv_b    = wall_b + 2u * 1048576u;
    unsigned short* wproj_b = wall_b + 3u * 1048576u;
    unsigned short* vtp     = (unsigned short*)(ws + (40u << 20)); // 8MB [bh][64][2048]
    unsigned short* qbuf    = (unsigned short*)(ws + (48u << 20)); // 8MB
    unsigned short* kbuf    = (unsigned short*)(ws + (56u << 20)); // 8MB
    float*          cost    = (float*)        (ws + (72u << 20));
    float*          sint    = (float*)        (ws + (72u << 20) + 262144);
    unsigned short* pO      = (unsigned short*)(ws + (80u << 20)); // 2 x 8MB partials (stride 4194304 elems)
    float*          lsum    = (float*)        (ws + (112u << 20)); // 2 x 256KB

    prep_bf16<<<8448, 256, 0, stream>>>(x, w_q, w_k, w_v, w_proj, xb, wall_b, cost, sint);

    gemm_qk<<<dim3(32, 16), 256, 0, stream>>>(xb, wqkv_b, cost, sint, qbuf, kbuf);
    gemm_v<<<dim3(32, 8), 256, 0, stream>>>(xb, wv_b, v1, lamb, vtp, out + 4194304);

    attn<<<1024, 256, 0, stream>>>(qbuf, kbuf, vtp, pO, lsum);

    gemm_proj<<<dim3(32, 8), 256, 0, stream>>>(pO, lsum, wproj_b, out);
}

// Round 20
// 126.409 us; speedup vs baseline: 1.0386x; 1.0322x over previous
//
#include <hip/hip_runtime.h>

// ---------- types ----------
typedef __bf16 bf16x8 __attribute__((ext_vector_type(8)));
typedef float f32x4 __attribute__((ext_vector_type(4)));
typedef float f32x16 __attribute__((ext_vector_type(16)));

__device__ __forceinline__ unsigned short f2bf(float f) {
    return __builtin_bit_cast(unsigned short, (__bf16)f);
}

__device__ __forceinline__ float bf2f(unsigned short u) {
    unsigned int x = ((unsigned int)u) << 16;
    return __builtin_bit_cast(float, x);
}

__device__ __forceinline__ unsigned int packbf2(float a, float b) {
    unsigned short lo = f2bf(a), hi = f2bf(b);
    return (unsigned int)lo | ((unsigned int)hi << 16);
}

__device__ __forceinline__ bf16x8 load_frag(const unsigned short* p) {
    int4 v = *reinterpret_cast<const int4*>(p);
    return __builtin_bit_cast(bf16x8, v);
}

__device__ __forceinline__ void gload_lds16(const unsigned short* g, unsigned short* l) {
    __builtin_amdgcn_global_load_lds((const __attribute__((address_space(1))) void*)g,
                                     (__attribute__((address_space(3))) void*)l, 16, 0, 0);
}

// ---------- prep: x + 4 weights -> bf16 (4 elems/thread); tail blocks build rope table ----------
__global__ __launch_bounds__(256) void prep_bf16(const float* __restrict__ x,
                                                 const float* __restrict__ wq,
                                                 const float* __restrict__ wk,
                                                 const float* __restrict__ wv,
                                                 const float* __restrict__ wp,
                                                 unsigned short* __restrict__ xb,
                                                 unsigned short* __restrict__ wall,
                                                 float* __restrict__ cost,
                                                 float* __restrict__ sint) {
    int bid = blockIdx.x;
    if (bid < 8192) {
        int i = (bid * 256 + threadIdx.x) * 4;            // 0..8M-4
        const float* src;
        unsigned short* dst;
        int soff, doff;
        if (i < (1 << 22)) {                               // x: 4M elems
            src = x; dst = xb; soff = i; doff = i;
        } else {
            int j = i - (1 << 22);                         // weights: 4x 1M elems
            int r = j >> 20;
            src = (r == 0) ? wq : ((r == 1) ? wk : ((r == 2) ? wv : wp));
            dst = wall; soff = j & 1048575; doff = j;
        }
        float4 v = *reinterpret_cast<const float4*>(&src[soff]);
        unsigned short tmp[4] = {f2bf(v.x), f2bf(v.y), f2bf(v.z), f2bf(v.w)};
        *reinterpret_cast<int2*>(&dst[doff]) = *reinterpret_cast<int2*>(tmp);
    } else {
        int i = (bid - 8192) * 256 + threadIdx.x;          // 2048*32
        int t = i >> 5, d = i & 31;
        float inv = powf(10000.0f, -(float)d / 32.0f);
        float f = (float)t * inv;
        cost[i] = cosf(f);
        sint[i] = sinf(f);
    }
}

// ---------- fused QKV GEMM dispatch: blockIdx.y<16 -> q/k (rms+rope), else v (lerp+transpose) ----------
// Bodies are fully disjoint (R16-proven); single launch saves a dispatch gap and packs tails.
__global__ __launch_bounds__(256) void gemm_qkv_all(const unsigned short* __restrict__ A,
                                                    const unsigned short* __restrict__ wall,  // [wq|wk|wv|wproj]
                                                    const float* __restrict__ cost,
                                                    const float* __restrict__ sint,
                                                    const float* __restrict__ v1,
                                                    const float* __restrict__ lamb_p,
                                                    unsigned short* __restrict__ qb,
                                                    unsigned short* __restrict__ kb,
                                                    unsigned short* __restrict__ vt,
                                                    float* __restrict__ outv1) {
    __shared__ __align__(16) unsigned short smem[2 * 128 * 72];   // 36864B (v path); qk uses first 32KB
    unsigned short* As = smem;
    unsigned short* Bs = smem + 128 * 64;
    int tid = threadIdx.x;
    int lane = tid & 63;
    int w = tid >> 6;
    int wm = w >> 1, wn = w & 1;
    int m0 = blockIdx.x * 128;
    int by = blockIdx.y;

    f32x4 acc[4][4] = {};
    int r8 = lane >> 3;
    int csrc = (lane & 7) ^ r8;      // pre-swizzled source 16B-unit (involution)

    if (by < 16) {
        // ---- Q/K path ----
        const unsigned short* B = wall;          // q rows 0..1023, k rows 1024..2047
        int n0 = by * 128;
        for (int k0 = 0; k0 < 1024; k0 += 64) {
            __syncthreads();
#pragma unroll
            for (int c = 0; c < 4; ++c) {
                int row = 32 * w + 8 * c + r8;
                gload_lds16(&A[(size_t)(m0 + row) * 1024 + k0 + csrc * 8], &As[(32 * w + 8 * c) * 64]);
                gload_lds16(&B[(size_t)(n0 + row) * 1024 + k0 + csrc * 8], &Bs[(32 * w + 8 * c) * 64]);
            }
            __syncthreads();
#pragma unroll
            for (int kk = 0; kk < 2; ++kk) {
                int col16 = kk * 4 + (lane >> 4);
                bf16x8 af[4], bfr[4];
#pragma unroll
                for (int i = 0; i < 4; ++i) {
                    int row = wm * 64 + i * 16 + (lane & 15);
                    af[i] = load_frag(&As[row * 64 + (col16 ^ (row & 7)) * 8]);
                }
#pragma unroll
                for (int j = 0; j < 4; ++j) {
                    int row = wn * 64 + j * 16 + (lane & 15);
                    bfr[j] = load_frag(&Bs[row * 64 + (col16 ^ (row & 7)) * 8]);
                }
#pragma unroll
                for (int i = 0; i < 4; ++i)
#pragma unroll
                    for (int j = 0; j < 4; ++j)
                        acc[i][j] = __builtin_amdgcn_mfma_f32_16x16x32_bf16(af[i], bfr[j], acc[i][j], 0, 0, 0);
            }
        }

        int r0 = (lane >> 4) * 4;
        int cc = lane & 15;
        int sec = by >> 3;                   // 0=q, 1=k
        int hh = (by & 7) * 2 + wn;          // head 0..15
        unsigned short* dst = (sec == 0) ? qb : kb;
        float sc = (sec == 0) ? (0.125f * 1.44269504088896f) : 1.0f;
#pragma unroll
        for (int i = 0; i < 4; ++i)
#pragma unroll
            for (int r = 0; r < 4; ++r) {
                float ss = 0.0f;
#pragma unroll
                for (int j = 0; j < 4; ++j) ss += acc[i][j][r] * acc[i][j][r];
                ss += __shfl_xor(ss, 1, 64);
                ss += __shfl_xor(ss, 2, 64);
                ss += __shfl_xor(ss, 4, 64);
                ss += __shfl_xor(ss, 8, 64);
                float rn = rsqrtf(ss * (1.0f / 64.0f) + 1e-6f);
                int mm = m0 + wm * 64 + i * 16 + r0 + r;
                int t = mm & 2047, b = mm >> 11;
                size_t rowb = ((size_t)((b * 16 + hh) * 2048 + t)) * 64;
#pragma unroll
                for (int j = 0; j < 2; ++j) {
                    int dm = j * 16 + cc;
                    float c = cost[t * 32 + dm], s_ = sint[t * 32 + dm];
                    float x1 = acc[i][j][r] * rn;
                    float x2 = acc[i][j + 2][r] * rn;
                    dst[rowb + dm]      = f2bf((x1 * c + x2 * s_) * sc);
                    dst[rowb + 32 + dm] = f2bf((x2 * c - x1 * s_) * sc);
                }
            }
    } else {
        // ---- V path ----
        const unsigned short* Bv = wall + 2u * 1048576u;  // wv rows
        int yv = by - 16;                    // 0..7
        int n0 = yv * 128;
        for (int k0 = 0; k0 < 1024; k0 += 64) {
            __syncthreads();
#pragma unroll
            for (int c = 0; c < 4; ++c) {
                int row = 32 * w + 8 * c + r8;
                gload_lds16(&A[(size_t)(m0 + row) * 1024 + k0 + csrc * 8], &As[(32 * w + 8 * c) * 64]);
                gload_lds16(&Bv[(size_t)(n0 + row) * 1024 + k0 + csrc * 8], &Bs[(32 * w + 8 * c) * 64]);
            }
            __syncthreads();
#pragma unroll
            for (int kk = 0; kk < 2; ++kk) {
                int col16 = kk * 4 + (lane >> 4);
                bf16x8 af[4], bfr[4];
#pragma unroll
                for (int i = 0; i < 4; ++i) {
                    int row = wm * 64 + i * 16 + (lane & 15);
                    af[i] = load_frag(&As[row * 64 + (col16 ^ (row & 7)) * 8]);
                }
#pragma unroll
                for (int j = 0; j < 4; ++j) {
                    int row = wn * 64 + j * 16 + (lane & 15);
                    bfr[j] = load_frag(&Bs[row * 64 + (col16 ^ (row & 7)) * 8]);
                }
#pragma unroll
                for (int i = 0; i < 4; ++i)
#pragma unroll
                    for (int j = 0; j < 4; ++j)
                        acc[i][j] = __builtin_amdgcn_mfma_f32_16x16x32_bf16(af[i], bfr[j], acc[i][j], 0, 0, 0);
            }
        }

        typedef unsigned short (*tile_t)[128][72];
        tile_t tile = reinterpret_cast<tile_t>(smem);
        int r0 = (lane >> 4) * 4;
        int cc = lane & 15;
        int hh = yv * 2 + wn;                // head 0..15
        float lam = lamb_p[0];
        float oml = 1.0f - lam;
        __syncthreads();                     // As/Bs dead; safe to overlay
#pragma unroll
        for (int i = 0; i < 4; ++i)
#pragma unroll
            for (int r = 0; r < 4; ++r) {
                int tl = wm * 64 + i * 16 + r0 + r;      // 0..127
                int mm = m0 + tl;
                int t = mm & 2047, b = mm >> 11;
                size_t v1row = ((size_t)((b * 2048 + t) * 16 + hh)) * 64;
#pragma unroll
                for (int j = 0; j < 4; ++j) {
                    int d = j * 16 + cc;
                    float v1v = v1[v1row + d];
                    outv1[v1row + d] = v1v;              // v1 passthrough output
                    tile[wn][tl][d] = f2bf(oml * acc[i][j][r] + lam * v1v);
                }
            }
        __syncthreads();

        int h2 = tid >> 7;                   // 0/1
        int idx = tid & 127;
        int rr2 = idx >> 2;                  // 0..31 -> d rows rr2, rr2+32
        int c2 = (idx & 3) * 8;              // 0,8,16,24
        int hhs = yv * 2 + h2;
        int t0 = m0 & 2047;
        int bb = m0 >> 11;
        unsigned short* dst = vt + ((size_t)(bb * 16 + hhs)) * 64 * 2048;
        unsigned short tmp[8];
#pragma unroll
        for (int tb = 0; tb < 128; tb += 32) {
#pragma unroll
            for (int j = 0; j < 8; ++j) tmp[j] = tile[h2][tb + c2 + j][rr2];
            *reinterpret_cast<int4*>(&dst[(size_t)rr2 * 2048 + t0 + tb + c2]) = *reinterpret_cast<int4*>(tmp);
#pragma unroll
            for (int j = 0; j < 8; ++j) tmp[j] = tile[h2][tb + c2 + j][rr2 + 32];
            *reinterpret_cast<int4*>(&dst[(size_t)(rr2 + 32) * 2048 + t0 + tb + c2]) = *reinterpret_cast<int4*>(tmp);
        }
    }
}

// ---------- proj GEMM with fused kv-split combine on the A side (proven R14) ----------
__global__ __launch_bounds__(256) void gemm_proj(const unsigned short* __restrict__ pO,
                                                 const float* __restrict__ lsum,
                                                 const unsigned short* __restrict__ B,
                                                 float* __restrict__ C) {
    __shared__ __align__(16) unsigned short As[128 * 64];
    __shared__ __align__(16) unsigned short Bs[128 * 64];
    int tid = threadIdx.x;
    int lane = tid & 63;
    int w = tid >> 6;
    int wm = w >> 1, wn = w & 1;
    int m0 = blockIdx.x * 128;
    int n0 = blockIdx.y * 128;

    f32x4 acc[4][4] = {};

    int r8 = lane >> 3;
    int c8 = lane & 7;
    int csrc = c8 ^ r8;

    for (int k0 = 0; k0 < 1024; k0 += 64) {
        int h = k0 >> 6;
        __syncthreads();
#pragma unroll
        for (int c = 0; c < 4; ++c) {
            int row = 32 * w + 8 * c + r8;
            int m = m0 + row;
            int bh = ((m >> 11) << 4) + h;
            int qi = m & 2047;
            int li = bh * 2048 + qi;
            size_t pi = (size_t)li * 64 + csrc * 8;
            int4 p0 = *reinterpret_cast<const int4*>(&pO[pi]);
            int4 p1 = *reinterpret_cast<const int4*>(&pO[4194304u + pi]);
            float linv = 1.0f / (lsum[li] + lsum[65536 + li]);
            const unsigned short* u0 = reinterpret_cast<const unsigned short*>(&p0);
            const unsigned short* u1 = reinterpret_cast<const unsigned short*>(&p1);
            unsigned short tmp[8];
#pragma unroll
            for (int j = 0; j < 8; ++j) tmp[j] = f2bf((bf2f(u0[j]) + bf2f(u1[j])) * linv);
            *reinterpret_cast<int4*>(&As[row * 64 + c8 * 8]) = *reinterpret_cast<int4*>(tmp);
            gload_lds16(&B[(size_t)(n0 + row) * 1024 + k0 + csrc * 8], &Bs[(32 * w + 8 * c) * 64]);
        }
        __syncthreads();
#pragma unroll
        for (int kk = 0; kk < 2; ++kk) {
            int col16 = kk * 4 + (lane >> 4);
            bf16x8 af[4], bfr[4];
#pragma unroll
            for (int i = 0; i < 4; ++i) {
                int row = wm * 64 + i * 16 + (lane & 15);
                af[i] = load_frag(&As[row * 64 + (col16 ^ (row & 7)) * 8]);
            }
#pragma unroll
            for (int j = 0; j < 4; ++j) {
                int row = wn * 64 + j * 16 + (lane & 15);
                bfr[j] = load_frag(&Bs[row * 64 + (col16 ^ (row & 7)) * 8]);
            }
#pragma unroll
            for (int i = 0; i < 4; ++i)
#pragma unroll
                for (int j = 0; j < 4; ++j)
                    acc[i][j] = __builtin_amdgcn_mfma_f32_16x16x32_bf16(af[i], bfr[j], acc[i][j], 0, 0, 0);
        }
    }
    int r0 = (lane >> 4) * 4;
    int cc = lane & 15;
#pragma unroll
    for (int i = 0; i < 4; ++i)
#pragma unroll
        for (int j = 0; j < 4; ++j)
#pragma unroll
            for (int r = 0; r < 4; ++r) {
                size_t m = m0 + wm * 64 + i * 16 + r0 + r;
                size_t n = n0 + wn * 64 + j * 16 + cc;
                C[m * 1024 + n] = acc[i][j][r];
            }
}

// ---------- flash attention, kv-split x2, causal, swapped-QK^T 32x32 MFMA ----------
// Proven R14 body: reg-staged LOADT, 2 barriers/tile, ntl-sequential liveness split.
__global__ __launch_bounds__(256) void attn(const unsigned short* __restrict__ qb,
                                            const unsigned short* __restrict__ kb,
                                            const unsigned short* __restrict__ vt,   // [bh][64][2048]
                                            unsigned short* __restrict__ pO,         // [ck][bh][2048][64] bf16
                                            float* __restrict__ lsum) {              // [ck][bh][2048] f32
    __shared__ __align__(16) unsigned short Ks[64][72];   // [kv][d]
    __shared__ __align__(16) unsigned short Vt[64][72];   // [d][kv]
    int tid = threadIdx.x;
    int lane = tid & 63;
    int w = tid >> 6;
    int hi = lane >> 5;
    int l31 = lane & 31;

    int bid = blockIdx.x;                    // 0..1023
    int bh = bid & 31;
    int r5 = bid >> 5;                       // 0..31
    int qt = 15 - (r5 >> 1);                 // heavy first
    int ck = r5 & 1;
    int q0 = qt * 128;
    const size_t base = (size_t)bh * 2048 * 64;
    const unsigned short* vtb = vt + (size_t)bh * 64 * 2048;
    int ktlo = ck * (qt + 1);
    int kthi = (ck + 1) * (qt + 1);          // exclusive

    bf16x8 qf[4];
    int qrow = q0 + w * 32 + l31;
#pragma unroll
    for (int kd = 0; kd < 4; ++kd)
        qf[kd] = load_frag(&qb[base + (size_t)qrow * 64 + kd * 16 + hi * 8]);

    f32x16 oacc[2] = {};
    float lrun = 0.0f;

    int srow = tid >> 3;            // 0..31
    int scol = (tid & 7) * 8;       // 0..56
    int4 kr0, kr1, vr0, vr1;
#define LOADT(kt_)                                                                                    \
    do {                                                                                              \
        kr0 = *reinterpret_cast<const int4*>(&kb[base + (size_t)((kt_)*64 + srow) * 64 + scol]);      \
        kr1 = *reinterpret_cast<const int4*>(&kb[base + (size_t)((kt_)*64 + srow + 32) * 64 + scol]); \
        vr0 = *reinterpret_cast<const int4*>(&vtb[(size_t)srow * 2048 + (kt_)*64 + scol]);            \
        vr1 = *reinterpret_cast<const int4*>(&vtb[(size_t)(srow + 32) * 2048 + (kt_)*64 + scol]);     \
    } while (0)

    int qwlo = q0 + w * 32;
    {
        LOADT(ktlo);
        for (int kt = ktlo; kt < kthi; ++kt) {
            __syncthreads();
            *reinterpret_cast<int4*>(&Ks[srow][scol]) = kr0;
            *reinterpret_cast<int4*>(&Ks[srow + 32][scol]) = kr1;
            *reinterpret_cast<int4*>(&Vt[srow][scol]) = vr0;
            *reinterpret_cast<int4*>(&Vt[srow + 32][scol]) = vr1;
            __syncthreads();
            if (kt + 1 < kthi) LOADT(kt + 1);

            if (kt * 64 <= qwlo + 31) {
                bool diag = (kt * 64 + 63 > qwlo);
                float rs01 = 0.0f, rs23 = 0.0f;
#pragma unroll
                for (int ntl = 0; ntl < 2; ++ntl) {
                    f32x16 sacc = {};
#pragma unroll
                    for (int kd = 0; kd < 4; ++kd) {
                        bf16x8 kf = load_frag(&Ks[ntl * 32 + l31][kd * 16 + hi * 8]);
                        sacc = __builtin_amdgcn_mfma_f32_32x32x16_bf16(kf, qf[kd], sacc, 0, 0, 0);
                    }

#pragma unroll
                    for (int r = 0; r < 16; ++r) {
                        float s = sacc[r];
                        if (diag) {
                            int kvg = kt * 64 + ntl * 32 + (r & 3) + 8 * (r >> 2) + 4 * hi;
                            if (kvg > qrow) s = -3.0e38f;
                        }
                        float e = __builtin_amdgcn_exp2f(s);
                        sacc[r] = e;
                        if (r & 2) rs23 += e; else rs01 += e;
                    }

                    unsigned int wAa[4], wBb[4];
#pragma unroll
                    for (int rr = 0; rr < 4; ++rr) {
                        wAa[rr] = packbf2(sacc[4 * rr + 0], sacc[4 * rr + 1]);
                        wBb[rr] = packbf2(sacc[4 * rr + 2], sacc[4 * rr + 3]);
                    }

#pragma unroll
                    for (int ks2 = 0; ks2 < 2; ++ks2) {
                        int b2 = ks2 * 2;
                        auto rA = __builtin_amdgcn_permlane32_swap(wAa[b2], wAa[b2 + 1], false, false);
                        auto rB = __builtin_amdgcn_permlane32_swap(wBb[b2], wBb[b2 + 1], false, false);
                        uint4 pa;
                        pa.x = rA[0];   // kv 16ks+8hi+{0,1}
                        pa.y = rB[0];   // +{2,3}
                        pa.z = rA[1];   // +{4,5}
                        pa.w = rB[1];   // +{6,7}
                        bf16x8 paf = __builtin_bit_cast(bf16x8, pa);
                        int ks = ntl * 2 + ks2;
#pragma unroll
                        for (int dt = 0; dt < 2; ++dt) {
                            bf16x8 vtf = load_frag(&Vt[dt * 32 + l31][ks * 16 + hi * 8]);
                            oacc[dt] = __builtin_amdgcn_mfma_f32_32x32x16_bf16(paf, vtf, oacc[dt], 0, 0, 0);
                        }
                    }
                }
                float rs = rs01 + rs23;
                rs += __shfl_xor(rs, 32, 64);
                lrun += rs;
            }
        }
    }

    unsigned short* po = pO + ((size_t)ck * 4194304u);
    float* ls = lsum + ck * 65536;
#pragma unroll
    for (int r = 0; r < 16; ++r) {
        int ql = (r & 3) + 8 * (r >> 2) + 4 * hi;
        int q = q0 + w * 32 + ql;
        size_t ro = ((size_t)bh * 2048 + q) * 64;
        po[ro + l31]      = f2bf(oacc[0][r]);
        po[ro + 32 + l31] = f2bf(oacc[1][r]);
    }
    if (hi == 0) ls[bh * 2048 + q0 + w * 32 + l31] = lrun;
#undef LOADT
}

// ---------- launch ----------
extern "C" void kernel_launch(void* const* d_in, const int* in_sizes, int n_in,
                              void* d_out, int out_size, void* d_ws, size_t ws_size,
                              hipStream_t stream) {
    const float* x      = (const float*)d_in[0];   // [2,2048,1024]
    const float* v1     = (const float*)d_in[1];   // [2,2048,16,64]
    const float* w_q    = (const float*)d_in[2];
    const float* w_k    = (const float*)d_in[3];
    const float* w_v    = (const float*)d_in[4];
    const float* w_proj = (const float*)d_in[5];
    const float* lamb   = (const float*)d_in[6];
    float* out = (float*)d_out;

    char* ws = (char*)d_ws;
    unsigned short* xb      = (unsigned short*)(ws + 0);           // 8MB
    unsigned short* wall_b  = (unsigned short*)(ws + (8u  << 20)); // 8MB: [wq|wk|wv|wproj]
    unsigned short* wproj_b = wall_b + 3u * 1048576u;
    unsigned short* vtp     = (unsigned short*)(ws + (40u << 20)); // 8MB [bh][64][2048]
    unsigned short* qbuf    = (unsigned short*)(ws + (48u << 20)); // 8MB
    unsigned short* kbuf    = (unsigned short*)(ws + (56u << 20)); // 8MB
    float*          cost    = (float*)        (ws + (72u << 20));
    float*          sint    = (float*)        (ws + (72u << 20) + 262144);
    unsigned short* pO      = (unsigned short*)(ws + (80u << 20)); // 2 x 8MB partials (stride 4194304 elems)
    float*          lsum    = (float*)        (ws + (112u << 20)); // 2 x 256KB

    prep_bf16<<<8448, 256, 0, stream>>>(x, w_q, w_k, w_v, w_proj, xb, wall_b, cost, sint);

    gemm_qkv_all<<<dim3(32, 24), 256, 0, stream>>>(xb, wall_b, cost, sint, v1, lamb,
                                                   qbuf, kbuf, vtp, out + 4194304);

    attn<<<1024, 256, 0, stream>>>(qbuf, kbuf, vtp, pO, lsum);

    gemm_proj<<<dim3(32, 8), 256, 0, stream>>>(pO, lsum, wproj_b, out);
}

// Round 21
// 124.524 us; speedup vs baseline: 1.0543x; 1.0151x over previous
//
#include <hip/hip_runtime.h>

// ---------- types ----------
typedef __bf16 bf16x8 __attribute__((ext_vector_type(8)));
typedef float f32x4 __attribute__((ext_vector_type(4)));
typedef float f32x16 __attribute__((ext_vector_type(16)));

__device__ __forceinline__ unsigned short f2bf(float f) {
    return __builtin_bit_cast(unsigned short, (__bf16)f);
}

__device__ __forceinline__ float bf2f(unsigned short u) {
    unsigned int x = ((unsigned int)u) << 16;
    return __builtin_bit_cast(float, x);
}

__device__ __forceinline__ unsigned int packbf2(float a, float b) {
    unsigned short lo = f2bf(a), hi = f2bf(b);
    return (unsigned int)lo | ((unsigned int)hi << 16);
}

__device__ __forceinline__ bf16x8 load_frag(const unsigned short* p) {
    int4 v = *reinterpret_cast<const int4*>(p);
    return __builtin_bit_cast(bf16x8, v);
}

__device__ __forceinline__ void gload_lds16(const unsigned short* g, unsigned short* l) {
    __builtin_amdgcn_global_load_lds((const __attribute__((address_space(1))) void*)g,
                                     (__attribute__((address_space(3))) void*)l, 16, 0, 0);
}

// ---------- prep: x + 4 weights -> bf16 (4 elems/thread); tail blocks build rope table ----------
__global__ __launch_bounds__(256) void prep_bf16(const float* __restrict__ x,
                                                 const float* __restrict__ wq,
                                                 const float* __restrict__ wk,
                                                 const float* __restrict__ wv,
                                                 const float* __restrict__ wp,
                                                 unsigned short* __restrict__ xb,
                                                 unsigned short* __restrict__ wall,
                                                 float* __restrict__ cost,
                                                 float* __restrict__ sint) {
    int bid = blockIdx.x;
    if (bid < 8192) {
        int i = (bid * 256 + threadIdx.x) * 4;            // 0..8M-4
        const float* src;
        unsigned short* dst;
        int soff, doff;
        if (i < (1 << 22)) {                               // x: 4M elems
            src = x; dst = xb; soff = i; doff = i;
        } else {
            int j = i - (1 << 22);                         // weights: 4x 1M elems
            int r = j >> 20;
            src = (r == 0) ? wq : ((r == 1) ? wk : ((r == 2) ? wv : wp));
            dst = wall; soff = j & 1048575; doff = j;
        }
        float4 v = *reinterpret_cast<const float4*>(&src[soff]);
        unsigned short tmp[4] = {f2bf(v.x), f2bf(v.y), f2bf(v.z), f2bf(v.w)};
        *reinterpret_cast<int2*>(&dst[doff]) = *reinterpret_cast<int2*>(tmp);
    } else {
        int i = (bid - 8192) * 256 + threadIdx.x;          // 2048*32
        int t = i >> 5, d = i & 31;
        float inv = powf(10000.0f, -(float)d / 32.0f);
        float f = (float)t * inv;
        cost[i] = cosf(f);
        sint[i] = sinf(f);
    }
}

// ---------- fused QKV GEMM dispatch: blockIdx.y<8 -> v (lerp+transpose, launches FIRST),
// else q/k (rms+rope). Bodies fully disjoint (R16/R20-proven); v-first shortens the tail.
__global__ __launch_bounds__(256) void gemm_qkv_all(const unsigned short* __restrict__ A,
                                                    const unsigned short* __restrict__ wall,  // [wq|wk|wv|wproj]
                                                    const float* __restrict__ cost,
                                                    const float* __restrict__ sint,
                                                    const float* __restrict__ v1,
                                                    const float* __restrict__ lamb_p,
                                                    unsigned short* __restrict__ qb,
                                                    unsigned short* __restrict__ kb,
                                                    unsigned short* __restrict__ vt,
                                                    float* __restrict__ outv1) {
    __shared__ __align__(16) unsigned short smem[2 * 128 * 72];   // 36864B (v path); qk uses first 32KB
    unsigned short* As = smem;
    unsigned short* Bs = smem + 128 * 64;
    int tid = threadIdx.x;
    int lane = tid & 63;
    int w = tid >> 6;
    int wm = w >> 1, wn = w & 1;
    int m0 = blockIdx.x * 128;
    int by = blockIdx.y;

    f32x4 acc[4][4] = {};
    int r8 = lane >> 3;
    int csrc = (lane & 7) ^ r8;      // pre-swizzled source 16B-unit (involution)

    if (by >= 8) {
        // ---- Q/K path (y = 8..23) ----
        const unsigned short* B = wall;          // q rows 0..1023, k rows 1024..2047
        int yq = by - 8;                         // 0..15
        int n0 = yq * 128;
        for (int k0 = 0; k0 < 1024; k0 += 64) {
            __syncthreads();
#pragma unroll
            for (int c = 0; c < 4; ++c) {
                int row = 32 * w + 8 * c + r8;
                gload_lds16(&A[(size_t)(m0 + row) * 1024 + k0 + csrc * 8], &As[(32 * w + 8 * c) * 64]);
                gload_lds16(&B[(size_t)(n0 + row) * 1024 + k0 + csrc * 8], &Bs[(32 * w + 8 * c) * 64]);
            }
            __syncthreads();
#pragma unroll
            for (int kk = 0; kk < 2; ++kk) {
                int col16 = kk * 4 + (lane >> 4);
                bf16x8 af[4], bfr[4];
#pragma unroll
                for (int i = 0; i < 4; ++i) {
                    int row = wm * 64 + i * 16 + (lane & 15);
                    af[i] = load_frag(&As[row * 64 + (col16 ^ (row & 7)) * 8]);
                }
#pragma unroll
                for (int j = 0; j < 4; ++j) {
                    int row = wn * 64 + j * 16 + (lane & 15);
                    bfr[j] = load_frag(&Bs[row * 64 + (col16 ^ (row & 7)) * 8]);
                }
#pragma unroll
                for (int i = 0; i < 4; ++i)
#pragma unroll
                    for (int j = 0; j < 4; ++j)
                        acc[i][j] = __builtin_amdgcn_mfma_f32_16x16x32_bf16(af[i], bfr[j], acc[i][j], 0, 0, 0);
            }
        }

        int r0 = (lane >> 4) * 4;
        int cc = lane & 15;
        int sec = yq >> 3;                   // 0=q, 1=k
        int hh = (yq & 7) * 2 + wn;          // head 0..15
        unsigned short* dst = (sec == 0) ? qb : kb;
        float sc = (sec == 0) ? (0.125f * 1.44269504088896f) : 1.0f;
#pragma unroll
        for (int i = 0; i < 4; ++i)
#pragma unroll
            for (int r = 0; r < 4; ++r) {
                float ss = 0.0f;
#pragma unroll
                for (int j = 0; j < 4; ++j) ss += acc[i][j][r] * acc[i][j][r];
                ss += __shfl_xor(ss, 1, 64);
                ss += __shfl_xor(ss, 2, 64);
                ss += __shfl_xor(ss, 4, 64);
                ss += __shfl_xor(ss, 8, 64);
                float rn = rsqrtf(ss * (1.0f / 64.0f) + 1e-6f);
                int mm = m0 + wm * 64 + i * 16 + r0 + r;
                int t = mm & 2047, b = mm >> 11;
                size_t rowb = ((size_t)((b * 16 + hh) * 2048 + t)) * 64;
#pragma unroll
                for (int j = 0; j < 2; ++j) {
                    int dm = j * 16 + cc;
                    float c = cost[t * 32 + dm], s_ = sint[t * 32 + dm];
                    float x1 = acc[i][j][r] * rn;
                    float x2 = acc[i][j + 2][r] * rn;
                    dst[rowb + dm]      = f2bf((x1 * c + x2 * s_) * sc);
                    dst[rowb + 32 + dm] = f2bf((x2 * c - x1 * s_) * sc);
                }
            }
    } else {
        // ---- V path (y = 0..7, launches first) ----
        const unsigned short* Bv = wall + 2u * 1048576u;  // wv rows
        int yv = by;                         // 0..7
        int n0 = yv * 128;
        for (int k0 = 0; k0 < 1024; k0 += 64) {
            __syncthreads();
#pragma unroll
            for (int c = 0; c < 4; ++c) {
                int row = 32 * w + 8 * c + r8;
                gload_lds16(&A[(size_t)(m0 + row) * 1024 + k0 + csrc * 8], &As[(32 * w + 8 * c) * 64]);
                gload_lds16(&Bv[(size_t)(n0 + row) * 1024 + k0 + csrc * 8], &Bs[(32 * w + 8 * c) * 64]);
            }
            __syncthreads();
#pragma unroll
            for (int kk = 0; kk < 2; ++kk) {
                int col16 = kk * 4 + (lane >> 4);
                bf16x8 af[4], bfr[4];
#pragma unroll
                for (int i = 0; i < 4; ++i) {
                    int row = wm * 64 + i * 16 + (lane & 15);
                    af[i] = load_frag(&As[row * 64 + (col16 ^ (row & 7)) * 8]);
                }
#pragma unroll
                for (int j = 0; j < 4; ++j) {
                    int row = wn * 64 + j * 16 + (lane & 15);
                    bfr[j] = load_frag(&Bs[row * 64 + (col16 ^ (row & 7)) * 8]);
                }
#pragma unroll
                for (int i = 0; i < 4; ++i)
#pragma unroll
                    for (int j = 0; j < 4; ++j)
                        acc[i][j] = __builtin_amdgcn_mfma_f32_16x16x32_bf16(af[i], bfr[j], acc[i][j], 0, 0, 0);
            }
        }

        typedef unsigned short (*tile_t)[128][72];
        tile_t tile = reinterpret_cast<tile_t>(smem);
        int r0 = (lane >> 4) * 4;
        int cc = lane & 15;
        int hh = yv * 2 + wn;                // head 0..15
        float lam = lamb_p[0];
        float oml = 1.0f - lam;
        __syncthreads();                     // As/Bs dead; safe to overlay
#pragma unroll
        for (int i = 0; i < 4; ++i)
#pragma unroll
            for (int r = 0; r < 4; ++r) {
                int tl = wm * 64 + i * 16 + r0 + r;      // 0..127
                int mm = m0 + tl;
                int t = mm & 2047, b = mm >> 11;
                size_t v1row = ((size_t)((b * 2048 + t) * 16 + hh)) * 64;
#pragma unroll
                for (int j = 0; j < 4; ++j) {
                    int d = j * 16 + cc;
                    float v1v = v1[v1row + d];
                    outv1[v1row + d] = v1v;              // v1 passthrough output
                    tile[wn][tl][d] = f2bf(oml * acc[i][j][r] + lam * v1v);
                }
            }
        __syncthreads();

        int h2 = tid >> 7;                   // 0/1
        int idx = tid & 127;
        int rr2 = idx >> 2;                  // 0..31 -> d rows rr2, rr2+32
        int c2 = (idx & 3) * 8;              // 0,8,16,24
        int hhs = yv * 2 + h2;
        int t0 = m0 & 2047;
        int bb = m0 >> 11;
        unsigned short* dst = vt + ((size_t)(bb * 16 + hhs)) * 64 * 2048;
        unsigned short tmp[8];
#pragma unroll
        for (int tb = 0; tb < 128; tb += 32) {
#pragma unroll
            for (int j = 0; j < 8; ++j) tmp[j] = tile[h2][tb + c2 + j][rr2];
            *reinterpret_cast<int4*>(&dst[(size_t)rr2 * 2048 + t0 + tb + c2]) = *reinterpret_cast<int4*>(tmp);
#pragma unroll
            for (int j = 0; j < 8; ++j) tmp[j] = tile[h2][tb + c2 + j][rr2 + 32];
            *reinterpret_cast<int4*>(&dst[(size_t)(rr2 + 32) * 2048 + t0 + tb + c2]) = *reinterpret_cast<int4*>(tmp);
        }
    }
}

// ---------- proj GEMM with fused kv-split combine on the A side (proven R14) ----------
__global__ __launch_bounds__(256) void gemm_proj(const unsigned short* __restrict__ pO,
                                                 const float* __restrict__ lsum,
                                                 const unsigned short* __restrict__ B,
                                                 float* __restrict__ C) {
    __shared__ __align__(16) unsigned short As[128 * 64];
    __shared__ __align__(16) unsigned short Bs[128 * 64];
    int tid = threadIdx.x;
    int lane = tid & 63;
    int w = tid >> 6;
    int wm = w >> 1, wn = w & 1;
    int m0 = blockIdx.x * 128;
    int n0 = blockIdx.y * 128;

    f32x4 acc[4][4] = {};

    int r8 = lane >> 3;
    int c8 = lane & 7;
    int csrc = c8 ^ r8;

    for (int k0 = 0; k0 < 1024; k0 += 64) {
        int h = k0 >> 6;
        __syncthreads();
#pragma unroll
        for (int c = 0; c < 4; ++c) {
            int row = 32 * w + 8 * c + r8;
            int m = m0 + row;
            int bh = ((m >> 11) << 4) + h;
            int qi = m & 2047;
            int li = bh * 2048 + qi;
            size_t pi = (size_t)li * 64 + csrc * 8;
            int4 p0 = *reinterpret_cast<const int4*>(&pO[pi]);
            int4 p1 = *reinterpret_cast<const int4*>(&pO[4194304u + pi]);
            float linv = 1.0f / (lsum[li] + lsum[65536 + li]);
            const unsigned short* u0 = reinterpret_cast<const unsigned short*>(&p0);
            const unsigned short* u1 = reinterpret_cast<const unsigned short*>(&p1);
            unsigned short tmp[8];
#pragma unroll
            for (int j = 0; j < 8; ++j) tmp[j] = f2bf((bf2f(u0[j]) + bf2f(u1[j])) * linv);
            *reinterpret_cast<int4*>(&As[row * 64 + c8 * 8]) = *reinterpret_cast<int4*>(tmp);
            gload_lds16(&B[(size_t)(n0 + row) * 1024 + k0 + csrc * 8], &Bs[(32 * w + 8 * c) * 64]);
        }
        __syncthreads();
#pragma unroll
        for (int kk = 0; kk < 2; ++kk) {
            int col16 = kk * 4 + (lane >> 4);
            bf16x8 af[4], bfr[4];
#pragma unroll
            for (int i = 0; i < 4; ++i) {
                int row = wm * 64 + i * 16 + (lane & 15);
                af[i] = load_frag(&As[row * 64 + (col16 ^ (row & 7)) * 8]);
            }
#pragma unroll
            for (int j = 0; j < 4; ++j) {
                int row = wn * 64 + j * 16 + (lane & 15);
                bfr[j] = load_frag(&Bs[row * 64 + (col16 ^ (row & 7)) * 8]);
            }
#pragma unroll
            for (int i = 0; i < 4; ++i)
#pragma unroll
                for (int j = 0; j < 4; ++j)
                    acc[i][j] = __builtin_amdgcn_mfma_f32_16x16x32_bf16(af[i], bfr[j], acc[i][j], 0, 0, 0);
        }
    }
    int r0 = (lane >> 4) * 4;
    int cc = lane & 15;
#pragma unroll
    for (int i = 0; i < 4; ++i)
#pragma unroll
        for (int j = 0; j < 4; ++j)
#pragma unroll
            for (int r = 0; r < 4; ++r) {
                size_t m = m0 + wm * 64 + i * 16 + r0 + r;
                size_t n = n0 + wn * 64 + j * 16 + cc;
                C[m * 1024 + n] = acc[i][j][r];
            }
}

// ---------- flash attention, kv-split x2, causal, swapped-QK^T 32x32 MFMA ----------
// Proven R14/R20 body: reg-staged LOADT, 2 barriers/tile, ntl-sequential liveness split.
__global__ __launch_bounds__(256) void attn(const unsigned short* __restrict__ qb,
                                            const unsigned short* __restrict__ kb,
                                            const unsigned short* __restrict__ vt,   // [bh][64][2048]
                                            unsigned short* __restrict__ pO,         // [ck][bh][2048][64] bf16
                                            float* __restrict__ lsum) {              // [ck][bh][2048] f32
    __shared__ __align__(16) unsigned short Ks[64][72];   // [kv][d]
    __shared__ __align__(16) unsigned short Vt[64][72];   // [d][kv]
    int tid = threadIdx.x;
    int lane = tid & 63;
    int w = tid >> 6;
    int hi = lane >> 5;
    int l31 = lane & 31;

    int bid = blockIdx.x;                    // 0..1023
    int bh = bid & 31;
    int r5 = bid >> 5;                       // 0..31
    int qt = 15 - (r5 >> 1);                 // heavy first
    int ck = r5 & 1;
    int q0 = qt * 128;
    const size_t base = (size_t)bh * 2048 * 64;
    const unsigned short* vtb = vt + (size_t)bh * 64 * 2048;
    int ktlo = ck * (qt + 1);
    int kthi = (ck + 1) * (qt + 1);          // exclusive

    bf16x8 qf[4];
    int qrow = q0 + w * 32 + l31;
#pragma unroll
    for (int kd = 0; kd < 4; ++kd)
        qf[kd] = load_frag(&qb[base + (size_t)qrow * 64 + kd * 16 + hi * 8]);

    f32x16 oacc[2] = {};
    float lrun = 0.0f;

    int srow = tid >> 3;            // 0..31
    int scol = (tid & 7) * 8;       // 0..56
    int4 kr0, kr1, vr0, vr1;
#define LOADT(kt_)                                                                                    \
    do {                                                                                              \
        kr0 = *reinterpret_cast<const int4*>(&kb[base + (size_t)((kt_)*64 + srow) * 64 + scol]);      \
        kr1 = *reinterpret_cast<const int4*>(&kb[base + (size_t)((kt_)*64 + srow + 32) * 64 + scol]); \
        vr0 = *reinterpret_cast<const int4*>(&vtb[(size_t)srow * 2048 + (kt_)*64 + scol]);            \
        vr1 = *reinterpret_cast<const int4*>(&vtb[(size_t)(srow + 32) * 2048 + (kt_)*64 + scol]);     \
    } while (0)

    int qwlo = q0 + w * 32;
    {
        LOADT(ktlo);
        for (int kt = ktlo; kt < kthi; ++kt) {
            __syncthreads();
            *reinterpret_cast<int4*>(&Ks[srow][scol]) = kr0;
            *reinterpret_cast<int4*>(&Ks[srow + 32][scol]) = kr1;
            *reinterpret_cast<int4*>(&Vt[srow][scol]) = vr0;
            *reinterpret_cast<int4*>(&Vt[srow + 32][scol]) = vr1;
            __syncthreads();
            if (kt + 1 < kthi) LOADT(kt + 1);

            if (kt * 64 <= qwlo + 31) {
                bool diag = (kt * 64 + 63 > qwlo);
                float rs01 = 0.0f, rs23 = 0.0f;
#pragma unroll
                for (int ntl = 0; ntl < 2; ++ntl) {
                    f32x16 sacc = {};
#pragma unroll
                    for (int kd = 0; kd < 4; ++kd) {
                        bf16x8 kf = load_frag(&Ks[ntl * 32 + l31][kd * 16 + hi * 8]);
                        sacc = __builtin_amdgcn_mfma_f32_32x32x16_bf16(kf, qf[kd], sacc, 0, 0, 0);
                    }

#pragma unroll
                    for (int r = 0; r < 16; ++r) {
                        float s = sacc[r];
                        if (diag) {
                            int kvg = kt * 64 + ntl * 32 + (r & 3) + 8 * (r >> 2) + 4 * hi;
                            if (kvg > qrow) s = -3.0e38f;
                        }
                        float e = __builtin_amdgcn_exp2f(s);
                        sacc[r] = e;
                        if (r & 2) rs23 += e; else rs01 += e;
                    }

                    unsigned int wAa[4], wBb[4];
#pragma unroll
                    for (int rr = 0; rr < 4; ++rr) {
                        wAa[rr] = packbf2(sacc[4 * rr + 0], sacc[4 * rr + 1]);
                        wBb[rr] = packbf2(sacc[4 * rr + 2], sacc[4 * rr + 3]);
                    }

#pragma unroll
                    for (int ks2 = 0; ks2 < 2; ++ks2) {
                        int b2 = ks2 * 2;
                        auto rA = __builtin_amdgcn_permlane32_swap(wAa[b2], wAa[b2 + 1], false, false);
                        auto rB = __builtin_amdgcn_permlane32_swap(wBb[b2], wBb[b2 + 1], false, false);
                        uint4 pa;
                        pa.x = rA[0];   // kv 16ks+8hi+{0,1}
                        pa.y = rB[0];   // +{2,3}
                        pa.z = rA[1];   // +{4,5}
                        pa.w = rB[1];   // +{6,7}
                        bf16x8 paf = __builtin_bit_cast(bf16x8, pa);
                        int ks = ntl * 2 + ks2;
#pragma unroll
                        for (int dt = 0; dt < 2; ++dt) {
                            bf16x8 vtf = load_frag(&Vt[dt * 32 + l31][ks * 16 + hi * 8]);
                            oacc[dt] = __builtin_amdgcn_mfma_f32_32x32x16_bf16(paf, vtf, oacc[dt], 0, 0, 0);
                        }
                    }
                }
                float rs = rs01 + rs23;
                rs += __shfl_xor(rs, 32, 64);
                lrun += rs;
            }
        }
    }

    unsigned short* po = pO + ((size_t)ck * 4194304u);
    float* ls = lsum + ck * 65536;
#pragma unroll
    for (int r = 0; r < 16; ++r) {
        int ql = (r & 3) + 8 * (r >> 2) + 4 * hi;
        int q = q0 + w * 32 + ql;
        size_t ro = ((size_t)bh * 2048 + q) * 64;
        po[ro + l31]      = f2bf(oacc[0][r]);
        po[ro + 32 + l31] = f2bf(oacc[1][r]);
    }
    if (hi == 0) ls[bh * 2048 + q0 + w * 32 + l31] = lrun;
#undef LOADT
}

// ---------- launch ----------
extern "C" void kernel_launch(void* const* d_in, const int* in_sizes, int n_in,
                              void* d_out, int out_size, void* d_ws, size_t ws_size,
                              hipStream_t stream) {
    const float* x      = (const float*)d_in[0];   // [2,2048,1024]
    const float* v1     = (const float*)d_in[1];   // [2,2048,16,64]
    const float* w_q    = (const float*)d_in[2];
    const float* w_k    = (const float*)d_in[3];
    const float* w_v    = (const float*)d_in[4];
    const float* w_proj = (const float*)d_in[5];
    const float* lamb   = (const float*)d_in[6];
    float* out = (float*)d_out;

    char* ws = (char*)d_ws;
    unsigned short* xb      = (unsigned short*)(ws + 0);           // 8MB
    unsigned short* wall_b  = (unsigned short*)(ws + (8u  << 20)); // 8MB: [wq|wk|wv|wproj]
    unsigned short* wproj_b = wall_b + 3u * 1048576u;
    unsigned short* vtp     = (unsigned short*)(ws + (40u << 20)); // 8MB [bh][64][2048]
    unsigned short* qbuf    = (unsigned short*)(ws + (48u << 20)); // 8MB
    unsigned short* kbuf    = (unsigned short*)(ws + (56u << 20)); // 8MB
    float*          cost    = (float*)        (ws + (72u << 20));
    float*          sint    = (float*)        (ws + (72u << 20) + 262144);
    unsigned short* pO      = (unsigned short*)(ws + (80u << 20)); // 2 x 8MB partials (stride 4194304 elems)
    float*          lsum    = (float*)        (ws + (112u << 20)); // 2 x 256KB

    prep_bf16<<<8448, 256, 0, stream>>>(x, w_q, w_k, w_v, w_proj, xb, wall_b, cost, sint);

    gemm_qkv_all<<<dim3(32, 24), 256, 0, stream>>>(xb, wall_b, cost, sint, v1, lamb,
                                                   qbuf, kbuf, vtp, out + 4194304);

    attn<<<1024, 256, 0, stream>>>(qbuf, kbuf, vtp, pO, lsum);

    gemm_proj<<<dim3(32, 8), 256, 0, stream>>>(pO, lsum, wproj_b, out);
}

// Round 22
// 116.411 us; speedup vs baseline: 1.1278x; 1.0697x over previous
//
#include <hip/hip_runtime.h>

// ---------- types ----------
typedef __bf16 bf16x8 __attribute__((ext_vector_type(8)));
typedef float f32x4 __attribute__((ext_vector_type(4)));
typedef float f32x16 __attribute__((ext_vector_type(16)));

__device__ __forceinline__ unsigned short f2bf(float f) {
    return __builtin_bit_cast(unsigned short, (__bf16)f);
}

__device__ __forceinline__ float bf2f(unsigned short u) {
    unsigned int x = ((unsigned int)u) << 16;
    return __builtin_bit_cast(float, x);
}

__device__ __forceinline__ unsigned int packbf2(float a, float b) {
    unsigned short lo = f2bf(a), hi = f2bf(b);
    return (unsigned int)lo | ((unsigned int)hi << 16);
}

__device__ __forceinline__ bf16x8 load_frag(const unsigned short* p) {
    int4 v = *reinterpret_cast<const int4*>(p);
    return __builtin_bit_cast(bf16x8, v);
}

__device__ __forceinline__ void gload_lds16(const unsigned short* g, unsigned short* l) {
    __builtin_amdgcn_global_load_lds((const __attribute__((address_space(1))) void*)g,
                                     (__attribute__((address_space(3))) void*)l, 16, 0, 0);
}

// ---------- prep: x + 4 weights -> bf16 (4 elems/thread); tail blocks build rope table ----------
__global__ __launch_bounds__(256) void prep_bf16(const float* __restrict__ x,
                                                 const float* __restrict__ wq,
                                                 const float* __restrict__ wk,
                                                 const float* __restrict__ wv,
                                                 const float* __restrict__ wp,
                                                 unsigned short* __restrict__ xb,
                                                 unsigned short* __restrict__ wall,
                                                 float* __restrict__ cost,
                                                 float* __restrict__ sint) {
    int bid = blockIdx.x;
    if (bid < 8192) {
        int i = (bid * 256 + threadIdx.x) * 4;            // 0..8M-4
        const float* src;
        unsigned short* dst;
        int soff, doff;
        if (i < (1 << 22)) {                               // x: 4M elems
            src = x; dst = xb; soff = i; doff = i;
        } else {
            int j = i - (1 << 22);                         // weights: 4x 1M elems
            int r = j >> 20;
            src = (r == 0) ? wq : ((r == 1) ? wk : ((r == 2) ? wv : wp));
            dst = wall; soff = j & 1048575; doff = j;
        }
        float4 v = *reinterpret_cast<const float4*>(&src[soff]);
        unsigned short tmp[4] = {f2bf(v.x), f2bf(v.y), f2bf(v.z), f2bf(v.w)};
        *reinterpret_cast<int2*>(&dst[doff]) = *reinterpret_cast<int2*>(tmp);
    } else {
        int i = (bid - 8192) * 256 + threadIdx.x;          // 2048*32
        int t = i >> 5, d = i & 31;
        float inv = powf(10000.0f, -(float)d / 32.0f);
        float f = (float)t * inv;
        cost[i] = cosf(f);
        sint[i] = sinf(f);
    }
}

// ---------- fused QKV GEMM, BM=64 tiles (grid 64 x 24): y<8 -> v (launches first), else q/k ----------
// 4 waves as 2x2: wm = w>>1 over 2x16 m-rows, wn = w&1 over 2 heads; acc[2][4].
// RoPE pair (d, d+32) = (j, j+2) stays register-local.
__global__ __launch_bounds__(256) void gemm_qkv_all(const unsigned short* __restrict__ A,
                                                    const unsigned short* __restrict__ wall,  // [wq|wk|wv|wproj]
                                                    const float* __restrict__ cost,
                                                    const float* __restrict__ sint,
                                                    const float* __restrict__ v1,
                                                    const float* __restrict__ lamb_p,
                                                    unsigned short* __restrict__ qb,
                                                    unsigned short* __restrict__ kb,
                                                    unsigned short* __restrict__ vt,
                                                    float* __restrict__ outv1) {
    __shared__ __align__(16) unsigned short smem[64 * 64 + 128 * 64];   // As 8KB + Bs 16KB = 24576B
    unsigned short* As = smem;                 // [64][64] linear
    unsigned short* Bs = smem + 64 * 64;       // [128][64] linear
    int tid = threadIdx.x;
    int lane = tid & 63;
    int w = tid >> 6;
    int wm = w >> 1, wn = w & 1;
    int m0 = blockIdx.x * 64;
    int by = blockIdx.y;

    f32x4 acc[2][4] = {};
    int r8 = lane >> 3;
    int ul = lane & 7;
    int csrc = ul ^ r8;              // pre-swizzled source 16B-unit (involution)

    const unsigned short* B = (by >= 8) ? wall : (wall + 2u * 1048576u);
    int n0 = ((by >= 8) ? (by - 8) & 7 : by) * 128 + ((by >= 16) ? 1024 : 0);
    // q: by 8..15 -> n0 = (by-8)*128 in wq rows; k: by 16..23 -> 1024 + (by-16)*128... careful:
    if (by >= 8) {
        int yq = by - 8;             // 0..15 over [q|k] rows 0..2047
        n0 = yq * 128;
    }

    for (int k0 = 0; k0 < 1024; k0 += 64) {
        __syncthreads();
        // A: 64 rows, each wave stages 16 rows (2 issues of 8)
#pragma unroll
        for (int i2 = 0; i2 < 2; ++i2) {
            int rowl = w * 16 + i2 * 8 + r8;
            gload_lds16(&A[(size_t)(m0 + rowl) * 1024 + k0 + csrc * 8], &As[(w * 16 + i2 * 8) * 64]);
        }
        // B: 128 rows, each wave stages 32 rows (4 issues of 8)
#pragma unroll
        for (int c = 0; c < 4; ++c) {
            int rowl = 32 * w + 8 * c + r8;
            gload_lds16(&B[(size_t)(n0 + rowl) * 1024 + k0 + csrc * 8], &Bs[(32 * w + 8 * c) * 64]);
        }
        __syncthreads();
#pragma unroll
        for (int kk = 0; kk < 2; ++kk) {
            int col16 = kk * 4 + (lane >> 4);
            bf16x8 af[2], bfr[4];
#pragma unroll
            for (int i = 0; i < 2; ++i) {
                int row = wm * 32 + i * 16 + (lane & 15);
                af[i] = load_frag(&As[row * 64 + (col16 ^ (row & 7)) * 8]);
            }
#pragma unroll
            for (int j = 0; j < 4; ++j) {
                int row = wn * 64 + j * 16 + (lane & 15);
                bfr[j] = load_frag(&Bs[row * 64 + (col16 ^ (row & 7)) * 8]);
            }
#pragma unroll
            for (int i = 0; i < 2; ++i)
#pragma unroll
                for (int j = 0; j < 4; ++j)
                    acc[i][j] = __builtin_amdgcn_mfma_f32_16x16x32_bf16(af[i], bfr[j], acc[i][j], 0, 0, 0);
        }
    }

    int r0 = (lane >> 4) * 4;
    int cc = lane & 15;
    if (by >= 8) {
        // ---- Q/K epilogue ----
        int yq = by - 8;
        int sec = yq >> 3;                   // 0=q, 1=k
        int hh = (yq & 7) * 2 + wn;          // head 0..15
        unsigned short* dst = (sec == 0) ? qb : kb;
        float sc = (sec == 0) ? (0.125f * 1.44269504088896f) : 1.0f;
#pragma unroll
        for (int i = 0; i < 2; ++i)
#pragma unroll
            for (int r = 0; r < 4; ++r) {
                float ss = 0.0f;
#pragma unroll
                for (int j = 0; j < 4; ++j) ss += acc[i][j][r] * acc[i][j][r];
                ss += __shfl_xor(ss, 1, 64);
                ss += __shfl_xor(ss, 2, 64);
                ss += __shfl_xor(ss, 4, 64);
                ss += __shfl_xor(ss, 8, 64);
                float rn = rsqrtf(ss * (1.0f / 64.0f) + 1e-6f);
                int mm = m0 + wm * 32 + i * 16 + r0 + r;
                int t = mm & 2047, b = mm >> 11;
                size_t rowb = ((size_t)((b * 16 + hh) * 2048 + t)) * 64;
#pragma unroll
                for (int j = 0; j < 2; ++j) {
                    int dm = j * 16 + cc;
                    float c = cost[t * 32 + dm], s_ = sint[t * 32 + dm];
                    float x1 = acc[i][j][r] * rn;
                    float x2 = acc[i][j + 2][r] * rn;
                    dst[rowb + dm]      = f2bf((x1 * c + x2 * s_) * sc);
                    dst[rowb + 32 + dm] = f2bf((x2 * c - x1 * s_) * sc);
                }
            }
    } else {
        // ---- V epilogue: lerp + v1 passthrough + in-LDS transpose ----
        typedef unsigned short (*tile_t)[64][72];
        tile_t tile = reinterpret_cast<tile_t>(smem);    // [2][64][72] = 18432B < 24576B overlay
        int yv = by;                         // 0..7
        int hh = yv * 2 + wn;                // head 0..15
        float lam = lamb_p[0];
        float oml = 1.0f - lam;
        __syncthreads();                     // As/Bs dead; safe to overlay
#pragma unroll
        for (int i = 0; i < 2; ++i)
#pragma unroll
            for (int r = 0; r < 4; ++r) {
                int tl = wm * 32 + i * 16 + r0 + r;      // 0..63
                int mm = m0 + tl;
                int t = mm & 2047, b = mm >> 11;
                size_t v1row = ((size_t)((b * 2048 + t) * 16 + hh)) * 64;
#pragma unroll
                for (int j = 0; j < 4; ++j) {
                    int d = j * 16 + cc;
                    float v1v = v1[v1row + d];
                    outv1[v1row + d] = v1v;              // v1 passthrough output
                    tile[wn][tl][d] = f2bf(oml * acc[i][j][r] + lam * v1v);
                }
            }
        __syncthreads();

        // transposed store: vt[bh][d][t0 + 0..63]
        int h2 = tid >> 7;                   // 0/1
        int idx = tid & 127;
        int rr2 = idx >> 2;                  // 0..31 -> d rows rr2, rr2+32
        int c2 = (idx & 3) * 8;              // 0,8,16,24
        int hhs = yv * 2 + h2;
        int t0 = m0 & 2047;
        int bb = m0 >> 11;
        unsigned short* dst = vt + ((size_t)(bb * 16 + hhs)) * 64 * 2048;
        unsigned short tmp[8];
#pragma unroll
        for (int tb = 0; tb < 64; tb += 32) {
#pragma unroll
            for (int j = 0; j < 8; ++j) tmp[j] = tile[h2][tb + c2 + j][rr2];
            *reinterpret_cast<int4*>(&dst[(size_t)rr2 * 2048 + t0 + tb + c2]) = *reinterpret_cast<int4*>(tmp);
#pragma unroll
            for (int j = 0; j < 8; ++j) tmp[j] = tile[h2][tb + c2 + j][rr2 + 32];
            *reinterpret_cast<int4*>(&dst[(size_t)(rr2 + 32) * 2048 + t0 + tb + c2]) = *reinterpret_cast<int4*>(tmp);
        }
    }
}

// ---------- proj GEMM, BM=64 (grid 64 x 8), fused kv-split combine on the A side ----------
__global__ __launch_bounds__(256) void gemm_proj(const unsigned short* __restrict__ pO,
                                                 const float* __restrict__ lsum,
                                                 const unsigned short* __restrict__ B,
                                                 float* __restrict__ C) {
    __shared__ __align__(16) unsigned short As[64 * 64];
    __shared__ __align__(16) unsigned short Bs[128 * 64];
    int tid = threadIdx.x;
    int lane = tid & 63;
    int w = tid >> 6;
    int wm = w >> 1, wn = w & 1;
    int m0 = blockIdx.x * 64;
    int n0 = blockIdx.y * 128;

    f32x4 acc[2][4] = {};

    int r8 = lane >> 3;
    int c8 = lane & 7;               // LDS slot this thread fills
    int csrc = c8 ^ r8;              // global 16B-unit it loads (involution)

    for (int k0 = 0; k0 < 1024; k0 += 64) {
        int h = k0 >> 6;
        __syncthreads();
        // A-combine: 64 rows, each wave 16 rows (2 passes of 8)
#pragma unroll
        for (int i2 = 0; i2 < 2; ++i2) {
            int rowl = w * 16 + i2 * 8 + r8;
            int m = m0 + rowl;
            int bh = ((m >> 11) << 4) + h;
            int qi = m & 2047;
            int li = bh * 2048 + qi;
            size_t pi = (size_t)li * 64 + csrc * 8;
            int4 p0 = *reinterpret_cast<const int4*>(&pO[pi]);
            int4 p1 = *reinterpret_cast<const int4*>(&pO[4194304u + pi]);
            float linv = 1.0f / (lsum[li] + lsum[65536 + li]);
            const unsigned short* u0 = reinterpret_cast<const unsigned short*>(&p0);
            const unsigned short* u1 = reinterpret_cast<const unsigned short*>(&p1);
            unsigned short tmp[8];
#pragma unroll
            for (int j = 0; j < 8; ++j) tmp[j] = f2bf((bf2f(u0[j]) + bf2f(u1[j])) * linv);
            *reinterpret_cast<int4*>(&As[rowl * 64 + c8 * 8]) = *reinterpret_cast<int4*>(tmp);
        }
        // B: 128 rows via gload
#pragma unroll
        for (int c = 0; c < 4; ++c) {
            int rowl = 32 * w + 8 * c + r8;
            gload_lds16(&B[(size_t)(n0 + rowl) * 1024 + k0 + csrc * 8], &Bs[(32 * w + 8 * c) * 64]);
        }
        __syncthreads();
#pragma unroll
        for (int kk = 0; kk < 2; ++kk) {
            int col16 = kk * 4 + (lane >> 4);
            bf16x8 af[2], bfr[4];
#pragma unroll
            for (int i = 0; i < 2; ++i) {
                int row = wm * 32 + i * 16 + (lane & 15);
                af[i] = load_frag(&As[row * 64 + (col16 ^ (row & 7)) * 8]);
            }
#pragma unroll
            for (int j = 0; j < 4; ++j) {
                int row = wn * 64 + j * 16 + (lane & 15);
                bfr[j] = load_frag(&Bs[row * 64 + (col16 ^ (row & 7)) * 8]);
            }
#pragma unroll
            for (int i = 0; i < 2; ++i)
#pragma unroll
                for (int j = 0; j < 4; ++j)
                    acc[i][j] = __builtin_amdgcn_mfma_f32_16x16x32_bf16(af[i], bfr[j], acc[i][j], 0, 0, 0);
        }
    }
    int r0 = (lane >> 4) * 4;
    int cc = lane & 15;
#pragma unroll
    for (int i = 0; i < 2; ++i)
#pragma unroll
        for (int j = 0; j < 4; ++j)
#pragma unroll
            for (int r = 0; r < 4; ++r) {
                size_t m = m0 + wm * 32 + i * 16 + r0 + r;
                size_t n = n0 + wn * 64 + j * 16 + cc;
                C[m * 1024 + n] = acc[i][j][r];
            }
}

// ---------- flash attention, kv-split x2, causal, swapped-QK^T 32x32 MFMA (proven R14/R20) ----------
__global__ __launch_bounds__(256) void attn(const unsigned short* __restrict__ qb,
                                            const unsigned short* __restrict__ kb,
                                            const unsigned short* __restrict__ vt,   // [bh][64][2048]
                                            unsigned short* __restrict__ pO,         // [ck][bh][2048][64] bf16
                                            float* __restrict__ lsum) {              // [ck][bh][2048] f32
    __shared__ __align__(16) unsigned short Ks[64][72];   // [kv][d]
    __shared__ __align__(16) unsigned short Vt[64][72];   // [d][kv]
    int tid = threadIdx.x;
    int lane = tid & 63;
    int w = tid >> 6;
    int hi = lane >> 5;
    int l31 = lane & 31;

    int bid = blockIdx.x;                    // 0..1023
    int bh = bid & 31;
    int r5 = bid >> 5;                       // 0..31
    int qt = 15 - (r5 >> 1);                 // heavy first
    int ck = r5 & 1;
    int q0 = qt * 128;
    const size_t base = (size_t)bh * 2048 * 64;
    const unsigned short* vtb = vt + (size_t)bh * 64 * 2048;
    int ktlo = ck * (qt + 1);
    int kthi = (ck + 1) * (qt + 1);          // exclusive

    bf16x8 qf[4];
    int qrow = q0 + w * 32 + l31;
#pragma unroll
    for (int kd = 0; kd < 4; ++kd)
        qf[kd] = load_frag(&qb[base + (size_t)qrow * 64 + kd * 16 + hi * 8]);

    f32x16 oacc[2] = {};
    float lrun = 0.0f;

    int srow = tid >> 3;            // 0..31
    int scol = (tid & 7) * 8;       // 0..56
    int4 kr0, kr1, vr0, vr1;
#define LOADT(kt_)                                                                                    \
    do {                                                                                              \
        kr0 = *reinterpret_cast<const int4*>(&kb[base + (size_t)((kt_)*64 + srow) * 64 + scol]);      \
        kr1 = *reinterpret_cast<const int4*>(&kb[base + (size_t)((kt_)*64 + srow + 32) * 64 + scol]); \
        vr0 = *reinterpret_cast<const int4*>(&vtb[(size_t)srow * 2048 + (kt_)*64 + scol]);            \
        vr1 = *reinterpret_cast<const int4*>(&vtb[(size_t)(srow + 32) * 2048 + (kt_)*64 + scol]);     \
    } while (0)

    int qwlo = q0 + w * 32;
    {
        LOADT(ktlo);
        for (int kt = ktlo; kt < kthi; ++kt) {
            __syncthreads();
            *reinterpret_cast<int4*>(&Ks[srow][scol]) = kr0;
            *reinterpret_cast<int4*>(&Ks[srow + 32][scol]) = kr1;
            *reinterpret_cast<int4*>(&Vt[srow][scol]) = vr0;
            *reinterpret_cast<int4*>(&Vt[srow + 32][scol]) = vr1;
            __syncthreads();
            if (kt + 1 < kthi) LOADT(kt + 1);

            if (kt * 64 <= qwlo + 31) {
                bool diag = (kt * 64 + 63 > qwlo);
                float rs01 = 0.0f, rs23 = 0.0f;
#pragma unroll
                for (int ntl = 0; ntl < 2; ++ntl) {
                    f32x16 sacc = {};
#pragma unroll
                    for (int kd = 0; kd < 4; ++kd) {
                        bf16x8 kf = load_frag(&Ks[ntl * 32 + l31][kd * 16 + hi * 8]);
                        sacc = __builtin_amdgcn_mfma_f32_32x32x16_bf16(kf, qf[kd], sacc, 0, 0, 0);
                    }

#pragma unroll
                    for (int r = 0; r < 16; ++r) {
                        float s = sacc[r];
                        if (diag) {
                            int kvg = kt * 64 + ntl * 32 + (r & 3) + 8 * (r >> 2) + 4 * hi;
                            if (kvg > qrow) s = -3.0e38f;
                        }
                        float e = __builtin_amdgcn_exp2f(s);
                        sacc[r] = e;
                        if (r & 2) rs23 += e; else rs01 += e;
                    }

                    unsigned int wAa[4], wBb[4];
#pragma unroll
                    for (int rr = 0; rr < 4; ++rr) {
                        wAa[rr] = packbf2(sacc[4 * rr + 0], sacc[4 * rr + 1]);
                        wBb[rr] = packbf2(sacc[4 * rr + 2], sacc[4 * rr + 3]);
                    }

#pragma unroll
                    for (int ks2 = 0; ks2 < 2; ++ks2) {
                        int b2 = ks2 * 2;
                        auto rA = __builtin_amdgcn_permlane32_swap(wAa[b2], wAa[b2 + 1], false, false);
                        auto rB = __builtin_amdgcn_permlane32_swap(wBb[b2], wBb[b2 + 1], false, false);
                        uint4 pa;
                        pa.x = rA[0];   // kv 16ks+8hi+{0,1}
                        pa.y = rB[0];   // +{2,3}
                        pa.z = rA[1];   // +{4,5}
                        pa.w = rB[1];   // +{6,7}
                        bf16x8 paf = __builtin_bit_cast(bf16x8, pa);
                        int ks = ntl * 2 + ks2;
#pragma unroll
                        for (int dt = 0; dt < 2; ++dt) {
                            bf16x8 vtf = load_frag(&Vt[dt * 32 + l31][ks * 16 + hi * 8]);
                            oacc[dt] = __builtin_amdgcn_mfma_f32_32x32x16_bf16(paf, vtf, oacc[dt], 0, 0, 0);
                        }
                    }
                }
                float rs = rs01 + rs23;
                rs += __shfl_xor(rs, 32, 64);
                lrun += rs;
            }
        }
    }

    unsigned short* po = pO + ((size_t)ck * 4194304u);
    float* ls = lsum + ck * 65536;
#pragma unroll
    for (int r = 0; r < 16; ++r) {
        int ql = (r & 3) + 8 * (r >> 2) + 4 * hi;
        int q = q0 + w * 32 + ql;
        size_t ro = ((size_t)bh * 2048 + q) * 64;
        po[ro + l31]      = f2bf(oacc[0][r]);
        po[ro + 32 + l31] = f2bf(oacc[1][r]);
    }
    if (hi == 0) ls[bh * 2048 + q0 + w * 32 + l31] = lrun;
#undef LOADT
}

// ---------- launch ----------
extern "C" void kernel_launch(void* const* d_in, const int* in_sizes, int n_in,
                              void* d_out, int out_size, void* d_ws, size_t ws_size,
                              hipStream_t stream) {
    const float* x      = (const float*)d_in[0];   // [2,2048,1024]
    const float* v1     = (const float*)d_in[1];   // [2,2048,16,64]
    const float* w_q    = (const float*)d_in[2];
    const float* w_k    = (const float*)d_in[3];
    const float* w_v    = (const float*)d_in[4];
    const float* w_proj = (const float*)d_in[5];
    const float* lamb   = (const float*)d_in[6];
    float* out = (float*)d_out;

    char* ws = (char*)d_ws;
    unsigned short* xb      = (unsigned short*)(ws + 0);           // 8MB
    unsigned short* wall_b  = (unsigned short*)(ws + (8u  << 20)); // 8MB: [wq|wk|wv|wproj]
    unsigned short* wproj_b = wall_b + 3u * 1048576u;
    unsigned short* vtp     = (unsigned short*)(ws + (40u << 20)); // 8MB [bh][64][2048]
    unsigned short* qbuf    = (unsigned short*)(ws + (48u << 20)); // 8MB
    unsigned short* kbuf    = (unsigned short*)(ws + (56u << 20)); // 8MB
    float*          cost    = (float*)        (ws + (72u << 20));
    float*          sint    = (float*)        (ws + (72u << 20) + 262144);
    unsigned short* pO      = (unsigned short*)(ws + (80u << 20)); // 2 x 8MB partials (stride 4194304 elems)
    float*          lsum    = (float*)        (ws + (112u << 20)); // 2 x 256KB

    prep_bf16<<<8448, 256, 0, stream>>>(x, w_q, w_k, w_v, w_proj, xb, wall_b, cost, sint);

    gemm_qkv_all<<<dim3(64, 24), 256, 0, stream>>>(xb, wall_b, cost, sint, v1, lamb,
                                                   qbuf, kbuf, vtp, out + 4194304);

    attn<<<1024, 256, 0, stream>>>(qbuf, kbuf, vtp, pO, lsum);

    gemm_proj<<<dim3(64, 8), 256, 0, stream>>>(pO, lsum, wproj_b, out);
}